// Round 8
// baseline (345.887 us; speedup 1.0000x reference)
//
#include <hip/hip_runtime.h>
#include <math.h>

#define NN 50000
#define NE 800000
#define NEP (NE + NN)   // edges incl self-loops
#define NGRAPH 500
#define NOUT 32
#define NBLK 196        // ceil(NN/256)

typedef _Float16 half4 __attribute__((ext_vector_type(4)));
typedef _Float16 half2v __attribute__((ext_vector_type(2)));

__device__ __forceinline__ float lrelu(float x) { return x > 0.f ? x : 0.2f * x; }
__device__ __forceinline__ half2v bch2(float f) { return __builtin_bit_cast(half2v, f); }

// monotone float<->uint key for atomicMax on floats (handles negatives)
__device__ __forceinline__ unsigned fkey(float f) {
    unsigned b = __float_as_uint(f);
    return (b & 0x80000000u) ? ~b : (b | 0x80000000u);
}
__device__ __forceinline__ float funkey(unsigned k) {
    unsigned b = (k & 0x80000000u) ? (k & 0x7fffffffu) : ~k;
    return __uint_as_float(b);
}

// ---------------- CSR construction ----------------

// pure atomic in-degree count (no pos array)
__global__ void k_count(const int* __restrict__ dst, int* __restrict__ cnt) {
    int e = blockIdx.x * blockDim.x + threadIdx.x;
    if (e < NE) atomicAdd(&cnt[dst[e]], 1);
}

// pass 1 block sums; also zero pool/cnt_g/gmaxU and compute UV + W16T (weight-only work)
__global__ __launch_bounds__(256) void k_scan1(const int* __restrict__ cnt, int* __restrict__ bsum,
                                               float* __restrict__ pool, float* __restrict__ cnt_g,
                                               unsigned* __restrict__ gmaxU,
                                               const float* __restrict__ gat_W,
                                               const float* __restrict__ att_src,
                                               const float* __restrict__ att_dst,
                                               float* __restrict__ UV,
                                               _Float16* __restrict__ W16T) {
    __shared__ int buf[256];
    int gid = blockIdx.x * 256 + threadIdx.x;
    int v = (gid < NN) ? (cnt[gid] + 1) : 0;
    buf[threadIdx.x] = v;
    for (int j = gid; j < NGRAPH * 256; j += NBLK * 256) pool[j] = 0.f;
    if (gid < NGRAPH) cnt_g[gid] = 0.f;
    if (gid < 4) gmaxU[gid] = 0u;
    // fp16 transposed gat_W: W16T[c*64+f] = gat_W[f*256+c]
    for (int j = gid; j < 64 * 256; j += NBLK * 256) {
        int c = j >> 6, f = j & 63;
        W16T[j] = (_Float16)gat_W[f * 256 + c];
    }
    // folded attention vectors: UV[f*8+o], o<4 -> U (src) head o, o>=4 -> V (dst) head o-4
    if (gid < 512) {
        int f = gid >> 3, o = gid & 7, h = o & 3;
        const float* av = (o < 4) ? att_src : att_dst;
        float s = 0.f;
#pragma unroll 8
        for (int c = 0; c < 64; ++c) s += gat_W[f * 256 + h * 64 + c] * av[h * 64 + c];
        UV[gid] = s;
    }
    __syncthreads();
    for (int off = 128; off; off >>= 1) {
        if (threadIdx.x < off) buf[threadIdx.x] += buf[threadIdx.x + off];
        __syncthreads();
    }
    if (threadIdx.x == 0) bsum[blockIdx.x] = buf[0];
}

__global__ __launch_bounds__(256) void k_scan3(const int* __restrict__ cnt,
                                               const int* __restrict__ bsum,
                                               int* __restrict__ row_ptr,
                                               int* __restrict__ cur,
                                               float* __restrict__ dinv,
                                               int* __restrict__ col) {
    __shared__ int sb[256];
    __shared__ int buf[256];
    int tid = threadIdx.x;
    int bv = (tid < NBLK) ? bsum[tid] : 0;
    sb[tid] = bv;
    __syncthreads();
    for (int off = 1; off < 256; off <<= 1) {
        int t = (tid >= off) ? sb[tid - off] : 0;
        __syncthreads();
        sb[tid] += t;
        __syncthreads();
    }
    int blockoff = (blockIdx.x == 0) ? 0 : sb[blockIdx.x - 1];
    int i = blockIdx.x * 256 + tid;
    int v = (i < NN) ? (cnt[i] + 1) : 0;
    buf[tid] = v;
    __syncthreads();
    for (int off = 1; off < 256; off <<= 1) {
        int t = (tid >= off) ? buf[tid - off] : 0;
        __syncthreads();
        buf[tid] += t;
        __syncthreads();
    }
    if (i < NN) {
        int rp = blockoff + buf[tid] - v;
        row_ptr[i] = rp;
        cur[i] = rp + 1;   // fill cursor: slot 0 reserved for self-loop
        dinv[i] = rsqrtf((float)(cnt[i] + 1));
        col[rp] = i;       // self-loop occupies slot 0 of each row
    }
    if (i == 0) row_ptr[NN] = NEP;
}

// atomic-cursor fill: no pos array round-trip
__global__ void k_fill(const int* __restrict__ src, const int* __restrict__ dst,
                       int* __restrict__ cur, int* __restrict__ col) {
    int idx = blockIdx.x * blockDim.x + threadIdx.x;
    if (idx < NE) {
        int d = dst[idx];
        int slot = atomicAdd(&cur[d], 1);
        col[slot] = src[idx];
    }
}

// ---------------- GEMM: hxs16 = dinv .* (x @ gcn_W)  (row pre-scaled for GCN agg) ----------------

__global__ __launch_bounds__(256) void k_gemm64(const float* __restrict__ A,
                                                const float* __restrict__ B,
                                                const float* __restrict__ dinv,
                                                _Float16* __restrict__ C16, int n) {
    __shared__ float Bs[64 * 64];    // 16 KB
    __shared__ float As[64 * 68];    // 17 KB, stride 68
    int tid = threadIdx.x;
    int rb = blockIdx.x * 64;
    for (int i = tid; i < 1024; i += 256) ((float4*)Bs)[i] = ((const float4*)B)[i];
    for (int i = tid; i < 1024; i += 256) {
        int r = i >> 4, c = i & 15;
        int row = rb + r; if (row >= n) row = n - 1;
        ((float4*)As)[r * 17 + c] = ((const float4*)A)[(size_t)row * 16 + c];
    }
    __syncthreads();
    int lane = tid & 63, wv = tid >> 6;
    int fl = lane & 15, sub = lane >> 4;
    int r0 = wv * 16 + sub * 4;
    const float4* Bs4 = (const float4*)Bs;
    float4 acc0 = {0,0,0,0}, acc1 = {0,0,0,0}, acc2 = {0,0,0,0}, acc3 = {0,0,0,0};
#pragma unroll 4
    for (int k = 0; k < 64; ++k) {
        float4 b4 = Bs4[k * 16 + fl];
        float a0 = As[(r0 + 0) * 68 + k];
        float a1 = As[(r0 + 1) * 68 + k];
        float a2 = As[(r0 + 2) * 68 + k];
        float a3 = As[(r0 + 3) * 68 + k];
        acc0.x += a0 * b4.x; acc0.y += a0 * b4.y; acc0.z += a0 * b4.z; acc0.w += a0 * b4.w;
        acc1.x += a1 * b4.x; acc1.y += a1 * b4.y; acc1.z += a1 * b4.z; acc1.w += a1 * b4.w;
        acc2.x += a2 * b4.x; acc2.y += a2 * b4.y; acc2.z += a2 * b4.z; acc2.w += a2 * b4.w;
        acc3.x += a3 * b4.x; acc3.y += a3 * b4.y; acc3.z += a3 * b4.z; acc3.w += a3 * b4.w;
    }
    int row = rb + r0;
    float d0 = dinv[row + 0 < n ? row + 0 : n - 1];
    float d1 = dinv[row + 1 < n ? row + 1 : n - 1];
    float d2 = dinv[row + 2 < n ? row + 2 : n - 1];
    float d3 = dinv[row + 3 < n ? row + 3 : n - 1];
    half4 h0, h1, h2, h3;
    h0.x=(_Float16)(acc0.x*d0); h0.y=(_Float16)(acc0.y*d0); h0.z=(_Float16)(acc0.z*d0); h0.w=(_Float16)(acc0.w*d0);
    h1.x=(_Float16)(acc1.x*d1); h1.y=(_Float16)(acc1.y*d1); h1.z=(_Float16)(acc1.z*d1); h1.w=(_Float16)(acc1.w*d1);
    h2.x=(_Float16)(acc2.x*d2); h2.y=(_Float16)(acc2.y*d2); h2.z=(_Float16)(acc2.z*d2); h2.w=(_Float16)(acc2.w*d2);
    h3.x=(_Float16)(acc3.x*d3); h3.y=(_Float16)(acc3.y*d3); h3.z=(_Float16)(acc3.z*d3); h3.w=(_Float16)(acc3.w*d3);
    if (row + 0 < n) ((half4*)(C16 + (size_t)(row + 0) * 64))[fl] = h0;
    if (row + 1 < n) ((half4*)(C16 + (size_t)(row + 1) * 64))[fl] = h1;
    if (row + 2 < n) ((half4*)(C16 + (size_t)(row + 2) * 64))[fl] = h2;
    if (row + 3 < n) ((half4*)(C16 + (size_t)(row + 3) * 64))[fl] = h3;
}

// ---------------- GCN aggregation (pre-scaled rows: pure gather+add) + fused logits ----------------

__global__ __launch_bounds__(256) void k_gcn_agg(const _Float16* __restrict__ hxs16,
                                                 const int* __restrict__ row_ptr,
                                                 const int* __restrict__ col,
                                                 const float* __restrict__ dinv,
                                                 const float* __restrict__ bias,
                                                 const float* __restrict__ UV,
                                                 _Float16* __restrict__ h16,
                                                 float* __restrict__ a_s,
                                                 float* __restrict__ a_d) {
    int wid = (blockIdx.x * blockDim.x + threadIdx.x) >> 6;
    int lane = threadIdx.x & 63;
    if (wid >= NN) return;
    int slot = lane >> 4;   // edge slot within 4-group (also head index for logits)
    int fl   = lane & 15;   // half4 index within row
    int s0 = row_ptr[wid], s1 = row_ptr[wid + 1];
    float di = dinv[wid];
    const half4* hx4 = (const half4*)hxs16;
    float ax = 0.f, ay = 0.f, az = 0.f, aw = 0.f;
    int k = s0 + slot;
    // 16 independent gathers in flight per wave iteration; no per-edge weight load
    for (; k + 12 < s1; k += 16) {
        int i0 = col[k], i1 = col[k + 4], i2 = col[k + 8], i3 = col[k + 12];
        half4 v0 = hx4[(size_t)i0 * 16 + fl];
        half4 v1 = hx4[(size_t)i1 * 16 + fl];
        half4 v2 = hx4[(size_t)i2 * 16 + fl];
        half4 v3 = hx4[(size_t)i3 * 16 + fl];
        ax += ((float)v0.x + (float)v1.x) + ((float)v2.x + (float)v3.x);
        ay += ((float)v0.y + (float)v1.y) + ((float)v2.y + (float)v3.y);
        az += ((float)v0.z + (float)v1.z) + ((float)v2.z + (float)v3.z);
        aw += ((float)v0.w + (float)v1.w) + ((float)v2.w + (float)v3.w);
    }
    for (; k < s1; k += 4) {
        half4 v = hx4[(size_t)col[k] * 16 + fl];
        ax += (float)v.x; ay += (float)v.y;
        az += (float)v.z; aw += (float)v.w;
    }
    ax += __shfl_xor(ax, 16); ax += __shfl_xor(ax, 32);
    ay += __shfl_xor(ay, 16); ay += __shfl_xor(ay, 32);
    az += __shfl_xor(az, 16); az += __shfl_xor(az, 32);
    aw += __shfl_xor(aw, 16); aw += __shfl_xor(aw, 32);
    // all 64 lanes now hold the full sums for feature group fl; apply dst-side scale
    float4 bb = ((const float4*)bias)[fl];
    float zx = fmaxf(ax * di + bb.x, 0.f);
    float zy = fmaxf(ay * di + bb.y, 0.f);
    float zz = fmaxf(az * di + bb.z, 0.f);
    float zw = fmaxf(aw * di + bb.w, 0.f);
    if (slot == 0) {
        half4 z;
        z.x = (_Float16)zx; z.y = (_Float16)zy; z.z = (_Float16)zz; z.w = (_Float16)zw;
        ((half4*)(h16 + (size_t)wid * 64))[fl] = z;
    }
    // fused attention logits: lane group slot computes head=slot partials
    int f0 = fl * 4;
    float ps = zx * UV[(f0 + 0) * 8 + slot] + zy * UV[(f0 + 1) * 8 + slot]
             + zz * UV[(f0 + 2) * 8 + slot] + zw * UV[(f0 + 3) * 8 + slot];
    float pd = zx * UV[(f0 + 0) * 8 + 4 + slot] + zy * UV[(f0 + 1) * 8 + 4 + slot]
             + zz * UV[(f0 + 2) * 8 + 4 + slot] + zw * UV[(f0 + 3) * 8 + 4 + slot];
    ps += __shfl_xor(ps, 1); pd += __shfl_xor(pd, 1);
    ps += __shfl_xor(ps, 2); pd += __shfl_xor(pd, 2);
    ps += __shfl_xor(ps, 4); pd += __shfl_xor(pd, 4);
    ps += __shfl_xor(ps, 8); pd += __shfl_xor(pd, 8);
    if (fl == 0) {
        a_s[wid * 4 + slot] = ps;
        a_d[wid * 4 + slot] = pd;
    }
}

// ---------------- global per-head max of a_s (safe softmax bound) ----------------

__global__ __launch_bounds__(256) void k_gmax(const float* __restrict__ a_s,
                                              unsigned* __restrict__ gmaxU) {
    __shared__ unsigned sm[4];
    int tid = threadIdx.x;
    if (tid < 4) sm[tid] = 0u;
    __syncthreads();
    float mx = -1e30f, my = -1e30f, mz = -1e30f, mw = -1e30f;
    int stride = gridDim.x * 256;
    for (int n = blockIdx.x * 256 + tid; n < NN; n += stride) {
        float4 v = ((const float4*)a_s)[n];
        mx = fmaxf(mx, v.x); my = fmaxf(my, v.y);
        mz = fmaxf(mz, v.z); mw = fmaxf(mw, v.w);
    }
    atomicMax(&sm[0], fkey(mx)); atomicMax(&sm[1], fkey(my));
    atomicMax(&sm[2], fkey(mz)); atomicMax(&sm[3], fkey(mw));
    __syncthreads();
    if (tid < 4) atomicMax(&gmaxU[tid], sm[tid]);
}

// ---------------- GAT aggregation: each h row loaded ONCE; 4 edge slots x 16 fl lanes ----------------
// unroll-4: 16 edges in flight per wave iteration (halves vmcnt waits vs unroll-2)

__global__ __launch_bounds__(256) void k_gat_h(const _Float16* __restrict__ h16,
                                               const float* __restrict__ a_s,
                                               const float* __restrict__ a_d,
                                               const int* __restrict__ row_ptr,
                                               const int* __restrict__ col,
                                               const unsigned* __restrict__ gmaxU,
                                               _Float16* __restrict__ aggH) {
    int tid = threadIdx.x;
    int wv = tid >> 6, lane = tid & 63;
    int wid = blockIdx.x * 4 + wv;           // NN == gridDim.x*4, always valid
    int slot = lane >> 4;                    // edge slot
    int fl = lane & 15;                      // half4 index within 64-feat h row

    int s0 = row_ptr[wid], s1 = row_ptr[wid + 1];
    float4 ad4 = ((const float4*)a_d)[wid];
    float M0 = lrelu(funkey(gmaxU[0]) + ad4.x);
    float M1 = lrelu(funkey(gmaxU[1]) + ad4.y);
    float M2 = lrelu(funkey(gmaxU[2]) + ad4.z);
    float M3 = lrelu(funkey(gmaxU[3]) + ad4.w);
    const half4* h4 = (const half4*)h16;
    const float4* as4 = (const float4*)a_s;

    float t0 = 1e-30f, t1 = 1e-30f, t2 = 1e-30f, t3 = 1e-30f;
    float4 A0 = {0,0,0,0}, A1 = {0,0,0,0}, A2 = {0,0,0,0}, A3 = {0,0,0,0};

#define EDGE_ACC(e4, v4)                                                      \
    {                                                                         \
        float w0 = __expf(lrelu((e4).x + ad4.x) - M0);                        \
        float w1 = __expf(lrelu((e4).y + ad4.y) - M1);                        \
        float w2 = __expf(lrelu((e4).z + ad4.z) - M2);                        \
        float w3 = __expf(lrelu((e4).w + ad4.w) - M3);                        \
        t0 += w0; t1 += w1; t2 += w2; t3 += w3;                               \
        float vx = (float)(v4).x, vy = (float)(v4).y;                         \
        float vz = (float)(v4).z, vw = (float)(v4).w;                         \
        A0.x += w0 * vx; A0.y += w0 * vy; A0.z += w0 * vz; A0.w += w0 * vw;   \
        A1.x += w1 * vx; A1.y += w1 * vy; A1.z += w1 * vz; A1.w += w1 * vw;   \
        A2.x += w2 * vx; A2.y += w2 * vy; A2.z += w2 * vz; A2.w += w2 * vw;   \
        A3.x += w3 * vx; A3.y += w3 * vy; A3.z += w3 * vz; A3.w += w3 * vw;   \
    }

    int k = s0 + slot;
    for (; k + 12 < s1; k += 16) {
        int ia = col[k], ib = col[k + 4], ic = col[k + 8], id = col[k + 12];
        float4 ea = as4[ia];
        float4 eb = as4[ib];
        float4 ec = as4[ic];
        float4 ed = as4[id];
        half4 va = h4[(size_t)ia * 16 + fl];
        half4 vb = h4[(size_t)ib * 16 + fl];
        half4 vc = h4[(size_t)ic * 16 + fl];
        half4 vd = h4[(size_t)id * 16 + fl];
        EDGE_ACC(ea, va)
        EDGE_ACC(eb, vb)
        EDGE_ACC(ec, vc)
        EDGE_ACC(ed, vd)
    }
    for (; k + 4 < s1; k += 8) {
        int ia = col[k], ib = col[k + 4];
        float4 ea = as4[ia];
        float4 eb = as4[ib];
        half4 va = h4[(size_t)ia * 16 + fl];
        half4 vb = h4[(size_t)ib * 16 + fl];
        EDGE_ACC(ea, va)
        EDGE_ACC(eb, vb)
    }
    if (k < s1) {
        int ia = col[k];
        float4 ea = as4[ia];
        half4 va = h4[(size_t)ia * 16 + fl];
        EDGE_ACC(ea, va)
    }
#undef EDGE_ACC

    // cross-slot reduction (values replicated over the 16 fl lanes of each slot)
#define REDX(x) x += __shfl_xor(x, 16); x += __shfl_xor(x, 32);
    REDX(t0) REDX(t1) REDX(t2) REDX(t3)
    REDX(A0.x) REDX(A0.y) REDX(A0.z) REDX(A0.w)
    REDX(A1.x) REDX(A1.y) REDX(A1.z) REDX(A1.w)
    REDX(A2.x) REDX(A2.y) REDX(A2.z) REDX(A2.w)
    REDX(A3.x) REDX(A3.y) REDX(A3.z) REDX(A3.w)
#undef REDX
    // slot s stores head s at its fl: address = wid*256 + slot*64 + fl*4 = wid*256 + lane*4
    float rsel = slot == 0 ? t0 : slot == 1 ? t1 : slot == 2 ? t2 : t3;
    float4 Asel = slot == 0 ? A0 : slot == 1 ? A1 : slot == 2 ? A2 : A3;
    float r = 1.f / rsel;
    half4 o;
    o.x = (_Float16)(Asel.x * r); o.y = (_Float16)(Asel.y * r);
    o.z = (_Float16)(Asel.z * r); o.w = (_Float16)(Asel.w * r);
    ((half4*)(aggH + (size_t)wid * 256))[lane] = o;
}

// ---------------- deferred projection, register-resident W column, fused pooling ----------------

__global__ __launch_bounds__(256) void k_post2(const _Float16* __restrict__ aggH,
                                               const _Float16* __restrict__ W16T,
                                               const float* __restrict__ gat_b,
                                               const int* __restrict__ batch,
                                               float* __restrict__ pool,
                                               float* __restrict__ cnt_g) {
    int tid = threadIdx.x;
    int lane = tid & 63;
    int wv = __builtin_amdgcn_readfirstlane(tid >> 6);
    int h = blockIdx.y;
    int c = h * 64 + lane;                    // global output column
    const float4* wp = (const float4*)(W16T + (size_t)c * 64);
    float4 Wb[8];
#pragma unroll
    for (int i = 0; i < 8; ++i) Wb[i] = wp[i];
    float gb = gat_b[c];

    int rbeg = (blockIdx.x * 4 + wv) * 32;
    int rend = rbeg + 32; if (rend > NN) rend = NN;

    float psum = 0.f;
    int curb = -1, rcnt = 0;
#pragma unroll 2
    for (int row = rbeg; row < rend; ++row) {
        int b = batch[row];
        if (b != curb) {
            if (curb >= 0) {
                atomicAdd(&pool[(size_t)curb * 256 + c], psum);
                if (h == 0 && lane == 0) atomicAdd(&cnt_g[curb], (float)rcnt);
            }
            psum = 0.f; rcnt = 0; curb = b;
        }
        const float4* ap = (const float4*)(aggH + (size_t)row * 256 + h * 64);
        float4 Ab[8];
#pragma unroll
        for (int i = 0; i < 8; ++i) Ab[i] = ap[i];
        float ac0 = 0.f, ac1 = 0.f, ac2 = 0.f, ac3 = 0.f;
#pragma unroll
        for (int i = 0; i < 8; ++i) {
            ac0 = __builtin_amdgcn_fdot2(bch2(Ab[i].x), bch2(Wb[i].x), ac0, false);
            ac1 = __builtin_amdgcn_fdot2(bch2(Ab[i].y), bch2(Wb[i].y), ac1, false);
            ac2 = __builtin_amdgcn_fdot2(bch2(Ab[i].z), bch2(Wb[i].z), ac2, false);
            ac3 = __builtin_amdgcn_fdot2(bch2(Ab[i].w), bch2(Wb[i].w), ac3, false);
        }
        float acc = (ac0 + ac1) + (ac2 + ac3);
        psum += fmaxf(acc + gb, 0.f);
        ++rcnt;
    }
    if (curb >= 0) {
        atomicAdd(&pool[(size_t)curb * 256 + c], psum);
        if (h == 0 && lane == 0) atomicAdd(&cnt_g[curb], (float)rcnt);
    }
}

// ---------------- output projection ----------------

__global__ void k_out(const float* __restrict__ pool, const float* __restrict__ cnt_g,
                      const float* __restrict__ W, const float* __restrict__ b,
                      float* __restrict__ out) {
    int idx = blockIdx.x * blockDim.x + threadIdx.x;
    if (idx >= NGRAPH * NOUT) return;
    int gg = idx >> 5, o = idx & 31;
    float c = cnt_g[gg];
    c = c > 1.f ? c : 1.f;
    float rinv = 1.f / c;
    const float* p = pool + (size_t)gg * 256;
    float acc = 0.f;
#pragma unroll 8
    for (int f = 0; f < 256; ++f) acc += p[f] * W[f * 32 + o];
    out[idx] = acc * rinv + b[o];
}

// ---------------- launch ----------------

extern "C" void kernel_launch(void* const* d_in, const int* in_sizes, int n_in,
                              void* d_out, int out_size, void* d_ws, size_t ws_size,
                              hipStream_t stream) {
    const float* x       = (const float*)d_in[0];
    const int*   eidx    = (const int*)d_in[1];
    const int*   batch   = (const int*)d_in[2];
    const float* gcn_W   = (const float*)d_in[3];
    const float* gcn_b   = (const float*)d_in[4];
    const float* gat_W   = (const float*)d_in[5];
    const float* att_src = (const float*)d_in[6];
    const float* att_dst = (const float*)d_in[7];
    const float* gat_b   = (const float*)d_in[8];
    const float* out_W   = (const float*)d_in[9];
    const float* out_b   = (const float*)d_in[10];
    float* out = (float*)d_out;

    const int* src = eidx;        // edge_index[0]
    const int* dst = eidx + NE;   // edge_index[1]

    size_t off = 0;
    auto carve = [&](size_t bytes) -> char* {
        char* p = (char*)d_ws + off;
        off += (bytes + 255) & ~(size_t)255;
        return p;
    };
    int*      cnt     = (int*)carve(NN * sizeof(int));
    int*      row_ptr = (int*)carve((NN + 1) * sizeof(int));
    int*      cur     = (int*)carve(NN * sizeof(int));
    int*      bsum    = (int*)carve(256 * sizeof(int));
    int*      colb    = (int*)carve((size_t)NEP * sizeof(int));
    float*    dinv    = (float*)carve(NN * sizeof(float));
    _Float16* hx16    = (_Float16*)carve((size_t)NN * 64 * sizeof(_Float16));
    _Float16* h16     = (_Float16*)carve((size_t)NN * 64 * sizeof(_Float16));
    _Float16* aggH16  = (_Float16*)carve((size_t)NN * 256 * sizeof(_Float16));
    float*    a_s     = (float*)carve((size_t)NN * 4 * sizeof(float));
    float*    a_d     = (float*)carve((size_t)NN * 4 * sizeof(float));
    float*    UV      = (float*)carve(64 * 8 * sizeof(float));
    _Float16* W16T    = (_Float16*)carve(64 * 256 * sizeof(_Float16));
    unsigned* gmaxU   = (unsigned*)carve(4 * sizeof(unsigned));
    float*    pool    = (float*)carve((size_t)NGRAPH * 256 * sizeof(float));
    float*    cnt_g   = (float*)carve(NGRAPH * sizeof(float));

    hipMemsetAsync(cnt, 0, NN * sizeof(int), stream);

    // CSR build (atomic-cursor fill; weight-side precompute folded into k_scan1)
    k_count<<<(NE + 255) / 256, 256, 0, stream>>>(dst, cnt);
    k_scan1<<<NBLK, 256, 0, stream>>>(cnt, bsum, pool, cnt_g, gmaxU,
                                      gat_W, att_src, att_dst, UV, W16T);
    k_scan3<<<NBLK, 256, 0, stream>>>(cnt, bsum, row_ptr, cur, dinv, colb);
    k_fill<<<(NE + 255) / 256, 256, 0, stream>>>(src, dst, cur, colb);

    // GCN (hx rows pre-scaled by dinv -> agg is pure gather+add)
    k_gemm64<<<(NN + 63) / 64, 256, 0, stream>>>(x, gcn_W, dinv, hx16, NN);
    k_gcn_agg<<<(NN * 64 + 255) / 256, 256, 0, stream>>>(hx16, row_ptr, colb, dinv, gcn_b,
                                                         UV, h16, a_s, a_d);

    // safe softmax bound, then GAT aggregation over h (128B/edge gather, unroll-4)
    k_gmax<<<128, 256, 0, stream>>>(a_s, gmaxU);
    k_gat_h<<<NN / 4, 256, 0, stream>>>(h16, a_s, a_d, row_ptr, colb, gmaxU, aggH16);

    // deferred projection + bias + relu + fused register pooling
    k_post2<<<dim3(391, 4), 256, 0, stream>>>(aggH16, W16T, gat_b, batch, pool, cnt_g);

    // output projection
    k_out<<<(NGRAPH * NOUT + 255) / 256, 256, 0, stream>>>(pool, cnt_g, out_W, out_b, out);
}

// Round 9
// 312.073 us; speedup vs baseline: 1.1084x; 1.1084x over previous
//
#include <hip/hip_runtime.h>
#include <math.h>

#define NN 50000
#define NE 800000
#define NEP (NE + NN)   // edges incl self-loops
#define NGRAPH 500
#define NOUT 32
#define NBLK 196        // ceil(NN/256)

typedef _Float16 half4 __attribute__((ext_vector_type(4)));
typedef _Float16 half2v __attribute__((ext_vector_type(2)));

__device__ __forceinline__ float lrelu(float x) { return x > 0.f ? x : 0.2f * x; }
__device__ __forceinline__ half2v bch2(float f) { return __builtin_bit_cast(half2v, f); }

// monotone float<->uint key for atomicMax on floats (handles negatives)
__device__ __forceinline__ unsigned fkey(float f) {
    unsigned b = __float_as_uint(f);
    return (b & 0x80000000u) ? ~b : (b | 0x80000000u);
}
__device__ __forceinline__ float funkey(unsigned k) {
    unsigned b = (k & 0x80000000u) ? (k & 0x7fffffffu) : ~k;
    return __uint_as_float(b);
}

// ---------------- CSR construction ----------------

__global__ void k_count(const int* __restrict__ dst, int* __restrict__ cnt,
                        int* __restrict__ pos) {
    int e = blockIdx.x * blockDim.x + threadIdx.x;
    if (e < NE) pos[e] = atomicAdd(&cnt[dst[e]], 1);
}

// pass 1 block sums; also zero pool/cnt_g/gmaxU and compute UV + W16T (weight-only work)
__global__ __launch_bounds__(256) void k_scan1(const int* __restrict__ cnt, int* __restrict__ bsum,
                                               float* __restrict__ pool, float* __restrict__ cnt_g,
                                               unsigned* __restrict__ gmaxU,
                                               const float* __restrict__ gat_W,
                                               const float* __restrict__ att_src,
                                               const float* __restrict__ att_dst,
                                               float* __restrict__ UV,
                                               _Float16* __restrict__ W16T) {
    __shared__ int buf[256];
    int gid = blockIdx.x * 256 + threadIdx.x;
    int v = (gid < NN) ? (cnt[gid] + 1) : 0;
    buf[threadIdx.x] = v;
    for (int j = gid; j < NGRAPH * 256; j += NBLK * 256) pool[j] = 0.f;
    if (gid < NGRAPH) cnt_g[gid] = 0.f;
    if (gid < 4) gmaxU[gid] = 0u;
    // fp16 transposed gat_W: W16T[c*64+f] = gat_W[f*256+c]
    for (int j = gid; j < 64 * 256; j += NBLK * 256) {
        int c = j >> 6, f = j & 63;
        W16T[j] = (_Float16)gat_W[f * 256 + c];
    }
    // folded attention vectors: UV[f*8+o], o<4 -> U (src) head o, o>=4 -> V (dst) head o-4
    if (gid < 512) {
        int f = gid >> 3, o = gid & 7, h = o & 3;
        const float* av = (o < 4) ? att_src : att_dst;
        float s = 0.f;
#pragma unroll 8
        for (int c = 0; c < 64; ++c) s += gat_W[f * 256 + h * 64 + c] * av[h * 64 + c];
        UV[gid] = s;
    }
    __syncthreads();
    for (int off = 128; off; off >>= 1) {
        if (threadIdx.x < off) buf[threadIdx.x] += buf[threadIdx.x + off];
        __syncthreads();
    }
    if (threadIdx.x == 0) bsum[blockIdx.x] = buf[0];
}

__global__ __launch_bounds__(256) void k_scan3(const int* __restrict__ cnt,
                                               const int* __restrict__ bsum,
                                               int* __restrict__ row_ptr,
                                               float* __restrict__ dinv,
                                               int* __restrict__ col) {
    __shared__ int sb[256];
    __shared__ int buf[256];
    int tid = threadIdx.x;
    int bv = (tid < NBLK) ? bsum[tid] : 0;
    sb[tid] = bv;
    __syncthreads();
    for (int off = 1; off < 256; off <<= 1) {
        int t = (tid >= off) ? sb[tid - off] : 0;
        __syncthreads();
        sb[tid] += t;
        __syncthreads();
    }
    int blockoff = (blockIdx.x == 0) ? 0 : sb[blockIdx.x - 1];
    int i = blockIdx.x * 256 + tid;
    int v = (i < NN) ? (cnt[i] + 1) : 0;
    buf[tid] = v;
    __syncthreads();
    for (int off = 1; off < 256; off <<= 1) {
        int t = (tid >= off) ? buf[tid - off] : 0;
        __syncthreads();
        buf[tid] += t;
        __syncthreads();
    }
    if (i < NN) {
        int rp = blockoff + buf[tid] - v;
        row_ptr[i] = rp;
        dinv[i] = rsqrtf((float)(cnt[i] + 1));
        col[rp] = i;   // self-loop occupies slot 0 of each row
    }
    if (i == 0) row_ptr[NN] = NEP;
}

__global__ void k_fill(const int* __restrict__ src, const int* __restrict__ dst,
                       const int* __restrict__ row_ptr, const int* __restrict__ pos,
                       int* __restrict__ col) {
    int idx = blockIdx.x * blockDim.x + threadIdx.x;
    if (idx < NE) {
        int d = dst[idx];
        col[row_ptr[d] + 1 + pos[idx]] = src[idx];
    }
}

// ---------------- GEMM: hxs16 = dinv .* (x @ gcn_W)  (row pre-scaled for GCN agg) ----------------

__global__ __launch_bounds__(256) void k_gemm64(const float* __restrict__ A,
                                                const float* __restrict__ B,
                                                const float* __restrict__ dinv,
                                                _Float16* __restrict__ C16, int n) {
    __shared__ float Bs[64 * 64];    // 16 KB
    __shared__ float As[64 * 68];    // 17 KB, stride 68
    int tid = threadIdx.x;
    int rb = blockIdx.x * 64;
    for (int i = tid; i < 1024; i += 256) ((float4*)Bs)[i] = ((const float4*)B)[i];
    for (int i = tid; i < 1024; i += 256) {
        int r = i >> 4, c = i & 15;
        int row = rb + r; if (row >= n) row = n - 1;
        ((float4*)As)[r * 17 + c] = ((const float4*)A)[(size_t)row * 16 + c];
    }
    __syncthreads();
    int lane = tid & 63, wv = tid >> 6;
    int fl = lane & 15, sub = lane >> 4;
    int r0 = wv * 16 + sub * 4;
    const float4* Bs4 = (const float4*)Bs;
    float4 acc0 = {0,0,0,0}, acc1 = {0,0,0,0}, acc2 = {0,0,0,0}, acc3 = {0,0,0,0};
#pragma unroll 4
    for (int k = 0; k < 64; ++k) {
        float4 b4 = Bs4[k * 16 + fl];
        float a0 = As[(r0 + 0) * 68 + k];
        float a1 = As[(r0 + 1) * 68 + k];
        float a2 = As[(r0 + 2) * 68 + k];
        float a3 = As[(r0 + 3) * 68 + k];
        acc0.x += a0 * b4.x; acc0.y += a0 * b4.y; acc0.z += a0 * b4.z; acc0.w += a0 * b4.w;
        acc1.x += a1 * b4.x; acc1.y += a1 * b4.y; acc1.z += a1 * b4.z; acc1.w += a1 * b4.w;
        acc2.x += a2 * b4.x; acc2.y += a2 * b4.y; acc2.z += a2 * b4.z; acc2.w += a2 * b4.w;
        acc3.x += a3 * b4.x; acc3.y += a3 * b4.y; acc3.z += a3 * b4.z; acc3.w += a3 * b4.w;
    }
    int row = rb + r0;
    float d0 = dinv[row + 0 < n ? row + 0 : n - 1];
    float d1 = dinv[row + 1 < n ? row + 1 : n - 1];
    float d2 = dinv[row + 2 < n ? row + 2 : n - 1];
    float d3 = dinv[row + 3 < n ? row + 3 : n - 1];
    half4 h0, h1, h2, h3;
    h0.x=(_Float16)(acc0.x*d0); h0.y=(_Float16)(acc0.y*d0); h0.z=(_Float16)(acc0.z*d0); h0.w=(_Float16)(acc0.w*d0);
    h1.x=(_Float16)(acc1.x*d1); h1.y=(_Float16)(acc1.y*d1); h1.z=(_Float16)(acc1.z*d1); h1.w=(_Float16)(acc1.w*d1);
    h2.x=(_Float16)(acc2.x*d2); h2.y=(_Float16)(acc2.y*d2); h2.z=(_Float16)(acc2.z*d2); h2.w=(_Float16)(acc2.w*d2);
    h3.x=(_Float16)(acc3.x*d3); h3.y=(_Float16)(acc3.y*d3); h3.z=(_Float16)(acc3.z*d3); h3.w=(_Float16)(acc3.w*d3);
    if (row + 0 < n) ((half4*)(C16 + (size_t)(row + 0) * 64))[fl] = h0;
    if (row + 1 < n) ((half4*)(C16 + (size_t)(row + 1) * 64))[fl] = h1;
    if (row + 2 < n) ((half4*)(C16 + (size_t)(row + 2) * 64))[fl] = h2;
    if (row + 3 < n) ((half4*)(C16 + (size_t)(row + 3) * 64))[fl] = h3;
}

// ---------------- GCN aggregation (pre-scaled rows: pure gather+add) + fused logits ----------------

__global__ __launch_bounds__(256) void k_gcn_agg(const _Float16* __restrict__ hxs16,
                                                 const int* __restrict__ row_ptr,
                                                 const int* __restrict__ col,
                                                 const float* __restrict__ dinv,
                                                 const float* __restrict__ bias,
                                                 const float* __restrict__ UV,
                                                 _Float16* __restrict__ h16,
                                                 float* __restrict__ a_s,
                                                 float* __restrict__ a_d) {
    int wid = (blockIdx.x * blockDim.x + threadIdx.x) >> 6;
    int lane = threadIdx.x & 63;
    if (wid >= NN) return;
    int slot = lane >> 4;   // edge slot within 4-group (also head index for logits)
    int fl   = lane & 15;   // half4 index within row
    int s0 = row_ptr[wid], s1 = row_ptr[wid + 1];
    float di = dinv[wid];
    const half4* hx4 = (const half4*)hxs16;
    float ax = 0.f, ay = 0.f, az = 0.f, aw = 0.f;
    int k = s0 + slot;
    // 16 independent gathers in flight per wave iteration; no per-edge weight load
    for (; k + 12 < s1; k += 16) {
        int i0 = col[k], i1 = col[k + 4], i2 = col[k + 8], i3 = col[k + 12];
        half4 v0 = hx4[(size_t)i0 * 16 + fl];
        half4 v1 = hx4[(size_t)i1 * 16 + fl];
        half4 v2 = hx4[(size_t)i2 * 16 + fl];
        half4 v3 = hx4[(size_t)i3 * 16 + fl];
        ax += ((float)v0.x + (float)v1.x) + ((float)v2.x + (float)v3.x);
        ay += ((float)v0.y + (float)v1.y) + ((float)v2.y + (float)v3.y);
        az += ((float)v0.z + (float)v1.z) + ((float)v2.z + (float)v3.z);
        aw += ((float)v0.w + (float)v1.w) + ((float)v2.w + (float)v3.w);
    }
    for (; k < s1; k += 4) {
        half4 v = hx4[(size_t)col[k] * 16 + fl];
        ax += (float)v.x; ay += (float)v.y;
        az += (float)v.z; aw += (float)v.w;
    }
    ax += __shfl_xor(ax, 16); ax += __shfl_xor(ax, 32);
    ay += __shfl_xor(ay, 16); ay += __shfl_xor(ay, 32);
    az += __shfl_xor(az, 16); az += __shfl_xor(az, 32);
    aw += __shfl_xor(aw, 16); aw += __shfl_xor(aw, 32);
    // all 64 lanes now hold the full sums for feature group fl; apply dst-side scale
    float4 bb = ((const float4*)bias)[fl];
    float zx = fmaxf(ax * di + bb.x, 0.f);
    float zy = fmaxf(ay * di + bb.y, 0.f);
    float zz = fmaxf(az * di + bb.z, 0.f);
    float zw = fmaxf(aw * di + bb.w, 0.f);
    if (slot == 0) {
        half4 z;
        z.x = (_Float16)zx; z.y = (_Float16)zy; z.z = (_Float16)zz; z.w = (_Float16)zw;
        ((half4*)(h16 + (size_t)wid * 64))[fl] = z;
    }
    // fused attention logits: lane group slot computes head=slot partials
    int f0 = fl * 4;
    float ps = zx * UV[(f0 + 0) * 8 + slot] + zy * UV[(f0 + 1) * 8 + slot]
             + zz * UV[(f0 + 2) * 8 + slot] + zw * UV[(f0 + 3) * 8 + slot];
    float pd = zx * UV[(f0 + 0) * 8 + 4 + slot] + zy * UV[(f0 + 1) * 8 + 4 + slot]
             + zz * UV[(f0 + 2) * 8 + 4 + slot] + zw * UV[(f0 + 3) * 8 + 4 + slot];
    ps += __shfl_xor(ps, 1); pd += __shfl_xor(pd, 1);
    ps += __shfl_xor(ps, 2); pd += __shfl_xor(pd, 2);
    ps += __shfl_xor(ps, 4); pd += __shfl_xor(pd, 4);
    ps += __shfl_xor(ps, 8); pd += __shfl_xor(pd, 8);
    if (fl == 0) {
        a_s[wid * 4 + slot] = ps;
        a_d[wid * 4 + slot] = pd;
    }
}

// ---------------- global per-head max of a_s (safe softmax bound) ----------------

__global__ __launch_bounds__(256) void k_gmax(const float* __restrict__ a_s,
                                              unsigned* __restrict__ gmaxU) {
    __shared__ unsigned sm[4];
    int tid = threadIdx.x;
    if (tid < 4) sm[tid] = 0u;
    __syncthreads();
    float mx = -1e30f, my = -1e30f, mz = -1e30f, mw = -1e30f;
    int stride = gridDim.x * 256;
    for (int n = blockIdx.x * 256 + tid; n < NN; n += stride) {
        float4 v = ((const float4*)a_s)[n];
        mx = fmaxf(mx, v.x); my = fmaxf(my, v.y);
        mz = fmaxf(mz, v.z); mw = fmaxf(mw, v.w);
    }
    atomicMax(&sm[0], fkey(mx)); atomicMax(&sm[1], fkey(my));
    atomicMax(&sm[2], fkey(mz)); atomicMax(&sm[3], fkey(mw));
    __syncthreads();
    if (tid < 4) atomicMax(&gmaxU[tid], sm[tid]);
}

// ---------------- GAT aggregation: each h row loaded ONCE; 4 edge slots x 16 fl lanes ----------------

__global__ __launch_bounds__(256) void k_gat_h(const _Float16* __restrict__ h16,
                                               const float* __restrict__ a_s,
                                               const float* __restrict__ a_d,
                                               const int* __restrict__ row_ptr,
                                               const int* __restrict__ col,
                                               const unsigned* __restrict__ gmaxU,
                                               _Float16* __restrict__ aggH) {
    int tid = threadIdx.x;
    int wv = tid >> 6, lane = tid & 63;
    int wid = blockIdx.x * 4 + wv;           // NN == gridDim.x*4, always valid
    int slot = lane >> 4;                    // edge slot
    int fl = lane & 15;                      // half4 index within 64-feat h row

    int s0 = row_ptr[wid], s1 = row_ptr[wid + 1];
    float4 ad4 = ((const float4*)a_d)[wid];
    float M0 = lrelu(funkey(gmaxU[0]) + ad4.x);
    float M1 = lrelu(funkey(gmaxU[1]) + ad4.y);
    float M2 = lrelu(funkey(gmaxU[2]) + ad4.z);
    float M3 = lrelu(funkey(gmaxU[3]) + ad4.w);
    const half4* h4 = (const half4*)h16;
    const float4* as4 = (const float4*)a_s;

    float t0 = 1e-30f, t1 = 1e-30f, t2 = 1e-30f, t3 = 1e-30f;
    float4 A0 = {0,0,0,0}, A1 = {0,0,0,0}, A2 = {0,0,0,0}, A3 = {0,0,0,0};

    int k = s0 + slot;
    for (; k + 4 < s1; k += 8) {
        int ia = col[k], ib = col[k + 4];
        float4 ea = as4[ia];
        float4 eb = as4[ib];
        half4 va = h4[(size_t)ia * 16 + fl];
        half4 vb = h4[(size_t)ib * 16 + fl];
        float wa0 = __expf(lrelu(ea.x + ad4.x) - M0);
        float wa1 = __expf(lrelu(ea.y + ad4.y) - M1);
        float wa2 = __expf(lrelu(ea.z + ad4.z) - M2);
        float wa3 = __expf(lrelu(ea.w + ad4.w) - M3);
        float wb0 = __expf(lrelu(eb.x + ad4.x) - M0);
        float wb1 = __expf(lrelu(eb.y + ad4.y) - M1);
        float wb2 = __expf(lrelu(eb.z + ad4.z) - M2);
        float wb3 = __expf(lrelu(eb.w + ad4.w) - M3);
        t0 += wa0 + wb0; t1 += wa1 + wb1; t2 += wa2 + wb2; t3 += wa3 + wb3;
        float vax = (float)va.x, vay = (float)va.y, vaz = (float)va.z, vaw = (float)va.w;
        float vbx = (float)vb.x, vby = (float)vb.y, vbz = (float)vb.z, vbw = (float)vb.w;
        A0.x += wa0 * vax + wb0 * vbx; A0.y += wa0 * vay + wb0 * vby;
        A0.z += wa0 * vaz + wb0 * vbz; A0.w += wa0 * vaw + wb0 * vbw;
        A1.x += wa1 * vax + wb1 * vbx; A1.y += wa1 * vay + wb1 * vby;
        A1.z += wa1 * vaz + wb1 * vbz; A1.w += wa1 * vaw + wb1 * vbw;
        A2.x += wa2 * vax + wb2 * vbx; A2.y += wa2 * vay + wb2 * vby;
        A2.z += wa2 * vaz + wb2 * vbz; A2.w += wa2 * vaw + wb2 * vbw;
        A3.x += wa3 * vax + wb3 * vbx; A3.y += wa3 * vay + wb3 * vby;
        A3.z += wa3 * vaz + wb3 * vbz; A3.w += wa3 * vaw + wb3 * vbw;
    }
    if (k < s1) {
        int ia = col[k];
        float4 ea = as4[ia];
        half4 va = h4[(size_t)ia * 16 + fl];
        float wa0 = __expf(lrelu(ea.x + ad4.x) - M0);
        float wa1 = __expf(lrelu(ea.y + ad4.y) - M1);
        float wa2 = __expf(lrelu(ea.z + ad4.z) - M2);
        float wa3 = __expf(lrelu(ea.w + ad4.w) - M3);
        t0 += wa0; t1 += wa1; t2 += wa2; t3 += wa3;
        float vax = (float)va.x, vay = (float)va.y, vaz = (float)va.z, vaw = (float)va.w;
        A0.x += wa0 * vax; A0.y += wa0 * vay; A0.z += wa0 * vaz; A0.w += wa0 * vaw;
        A1.x += wa1 * vax; A1.y += wa1 * vay; A1.z += wa1 * vaz; A1.w += wa1 * vaw;
        A2.x += wa2 * vax; A2.y += wa2 * vay; A2.z += wa2 * vaz; A2.w += wa2 * vaw;
        A3.x += wa3 * vax; A3.y += wa3 * vay; A3.z += wa3 * vaz; A3.w += wa3 * vaw;
    }
    // cross-slot reduction (values replicated over the 16 fl lanes of each slot)
#define REDX(x) x += __shfl_xor(x, 16); x += __shfl_xor(x, 32);
    REDX(t0) REDX(t1) REDX(t2) REDX(t3)
    REDX(A0.x) REDX(A0.y) REDX(A0.z) REDX(A0.w)
    REDX(A1.x) REDX(A1.y) REDX(A1.z) REDX(A1.w)
    REDX(A2.x) REDX(A2.y) REDX(A2.z) REDX(A2.w)
    REDX(A3.x) REDX(A3.y) REDX(A3.z) REDX(A3.w)
#undef REDX
    // slot s stores head s at its fl: address = wid*256 + slot*64 + fl*4 = wid*256 + lane*4
    float rsel = slot == 0 ? t0 : slot == 1 ? t1 : slot == 2 ? t2 : t3;
    float4 Asel = slot == 0 ? A0 : slot == 1 ? A1 : slot == 2 ? A2 : A3;
    float r = 1.f / rsel;
    half4 o;
    o.x = (_Float16)(Asel.x * r); o.y = (_Float16)(Asel.y * r);
    o.z = (_Float16)(Asel.z * r); o.w = (_Float16)(Asel.w * r);
    ((half4*)(aggH + (size_t)wid * 256))[lane] = o;
}

// ---------------- deferred projection, register-resident W column, fused pooling ----------------

__global__ __launch_bounds__(256) void k_post2(const _Float16* __restrict__ aggH,
                                               const _Float16* __restrict__ W16T,
                                               const float* __restrict__ gat_b,
                                               const int* __restrict__ batch,
                                               float* __restrict__ pool,
                                               float* __restrict__ cnt_g) {
    int tid = threadIdx.x;
    int lane = tid & 63;
    int wv = __builtin_amdgcn_readfirstlane(tid >> 6);
    int h = blockIdx.y;
    int c = h * 64 + lane;                    // global output column
    const float4* wp = (const float4*)(W16T + (size_t)c * 64);
    float4 Wb[8];
#pragma unroll
    for (int i = 0; i < 8; ++i) Wb[i] = wp[i];
    float gb = gat_b[c];

    int rbeg = (blockIdx.x * 4 + wv) * 32;
    int rend = rbeg + 32; if (rend > NN) rend = NN;

    float psum = 0.f;
    int curb = -1, rcnt = 0;
#pragma unroll 2
    for (int row = rbeg; row < rend; ++row) {
        int b = batch[row];
        if (b != curb) {
            if (curb >= 0) {
                atomicAdd(&pool[(size_t)curb * 256 + c], psum);
                if (h == 0 && lane == 0) atomicAdd(&cnt_g[curb], (float)rcnt);
            }
            psum = 0.f; rcnt = 0; curb = b;
        }
        const float4* ap = (const float4*)(aggH + (size_t)row * 256 + h * 64);
        float4 Ab[8];
#pragma unroll
        for (int i = 0; i < 8; ++i) Ab[i] = ap[i];
        float ac0 = 0.f, ac1 = 0.f, ac2 = 0.f, ac3 = 0.f;
#pragma unroll
        for (int i = 0; i < 8; ++i) {
            ac0 = __builtin_amdgcn_fdot2(bch2(Ab[i].x), bch2(Wb[i].x), ac0, false);
            ac1 = __builtin_amdgcn_fdot2(bch2(Ab[i].y), bch2(Wb[i].y), ac1, false);
            ac2 = __builtin_amdgcn_fdot2(bch2(Ab[i].z), bch2(Wb[i].z), ac2, false);
            ac3 = __builtin_amdgcn_fdot2(bch2(Ab[i].w), bch2(Wb[i].w), ac3, false);
        }
        float acc = (ac0 + ac1) + (ac2 + ac3);
        psum += fmaxf(acc + gb, 0.f);
        ++rcnt;
    }
    if (curb >= 0) {
        atomicAdd(&pool[(size_t)curb * 256 + c], psum);
        if (h == 0 && lane == 0) atomicAdd(&cnt_g[curb], (float)rcnt);
    }
}

// ---------------- output projection ----------------

__global__ void k_out(const float* __restrict__ pool, const float* __restrict__ cnt_g,
                      const float* __restrict__ W, const float* __restrict__ b,
                      float* __restrict__ out) {
    int idx = blockIdx.x * blockDim.x + threadIdx.x;
    if (idx >= NGRAPH * NOUT) return;
    int gg = idx >> 5, o = idx & 31;
    float c = cnt_g[gg];
    c = c > 1.f ? c : 1.f;
    float rinv = 1.f / c;
    const float* p = pool + (size_t)gg * 256;
    float acc = 0.f;
#pragma unroll 8
    for (int f = 0; f < 256; ++f) acc += p[f] * W[f * 32 + o];
    out[idx] = acc * rinv + b[o];
}

// ---------------- launch ----------------

extern "C" void kernel_launch(void* const* d_in, const int* in_sizes, int n_in,
                              void* d_out, int out_size, void* d_ws, size_t ws_size,
                              hipStream_t stream) {
    const float* x       = (const float*)d_in[0];
    const int*   eidx    = (const int*)d_in[1];
    const int*   batch   = (const int*)d_in[2];
    const float* gcn_W   = (const float*)d_in[3];
    const float* gcn_b   = (const float*)d_in[4];
    const float* gat_W   = (const float*)d_in[5];
    const float* att_src = (const float*)d_in[6];
    const float* att_dst = (const float*)d_in[7];
    const float* gat_b   = (const float*)d_in[8];
    const float* out_W   = (const float*)d_in[9];
    const float* out_b   = (const float*)d_in[10];
    float* out = (float*)d_out;

    const int* src = eidx;        // edge_index[0]
    const int* dst = eidx + NE;   // edge_index[1]

    size_t off = 0;
    auto carve = [&](size_t bytes) -> char* {
        char* p = (char*)d_ws + off;
        off += (bytes + 255) & ~(size_t)255;
        return p;
    };
    int*      cnt     = (int*)carve(NN * sizeof(int));
    int*      pos     = (int*)carve((size_t)NE * sizeof(int));
    int*      row_ptr = (int*)carve((NN + 1) * sizeof(int));
    int*      bsum    = (int*)carve(256 * sizeof(int));
    int*      colb    = (int*)carve((size_t)NEP * sizeof(int));
    float*    dinv    = (float*)carve(NN * sizeof(float));
    _Float16* hx16    = (_Float16*)carve((size_t)NN * 64 * sizeof(_Float16));
    _Float16* h16     = (_Float16*)carve((size_t)NN * 64 * sizeof(_Float16));
    _Float16* aggH16  = (_Float16*)carve((size_t)NN * 256 * sizeof(_Float16));
    float*    a_s     = (float*)carve((size_t)NN * 4 * sizeof(float));
    float*    a_d     = (float*)carve((size_t)NN * 4 * sizeof(float));
    float*    UV      = (float*)carve(64 * 8 * sizeof(float));
    _Float16* W16T    = (_Float16*)carve(64 * 256 * sizeof(_Float16));
    unsigned* gmaxU   = (unsigned*)carve(4 * sizeof(unsigned));
    float*    pool    = (float*)carve((size_t)NGRAPH * 256 * sizeof(float));
    float*    cnt_g   = (float*)carve(NGRAPH * sizeof(float));

    hipMemsetAsync(cnt, 0, NN * sizeof(int), stream);

    // CSR build (+ weight-side precompute folded into k_scan1)
    k_count<<<(NE + 255) / 256, 256, 0, stream>>>(dst, cnt, pos);
    k_scan1<<<NBLK, 256, 0, stream>>>(cnt, bsum, pool, cnt_g, gmaxU,
                                      gat_W, att_src, att_dst, UV, W16T);
    k_scan3<<<NBLK, 256, 0, stream>>>(cnt, bsum, row_ptr, dinv, colb);
    k_fill<<<(NE + 255) / 256, 256, 0, stream>>>(src, dst, row_ptr, pos, colb);

    // GCN (hx rows pre-scaled by dinv -> agg is pure gather+add)
    k_gemm64<<<(NN + 63) / 64, 256, 0, stream>>>(x, gcn_W, dinv, hx16, NN);
    k_gcn_agg<<<(NN * 64 + 255) / 256, 256, 0, stream>>>(hx16, row_ptr, colb, dinv, gcn_b,
                                                         UV, h16, a_s, a_d);

    // safe softmax bound, then GAT aggregation over h (128B/edge gather, loaded once)
    k_gmax<<<128, 256, 0, stream>>>(a_s, gmaxU);
    k_gat_h<<<NN / 4, 256, 0, stream>>>(h16, a_s, a_d, row_ptr, colb, gmaxU, aggH16);

    // deferred projection + bias + relu + fused register pooling
    k_post2<<<dim3(391, 4), 256, 0, stream>>>(aggH16, W16T, gat_b, batch, pool, cnt_g);

    // output projection
    k_out<<<(NGRAPH * NOUT + 255) / 256, 256, 0, stream>>>(pool, cnt_g, out_W, out_b, out);
}

// Round 10
// 289.610 us; speedup vs baseline: 1.1943x; 1.0776x over previous
//
#include <hip/hip_runtime.h>
#include <math.h>

#define NN 50000
#define NE 800000
#define NEP (NE + NN)   // edges incl self-loops
#define NGRAPH 500
#define NOUT 32
#define NBLK 196        // ceil(NN/256)

typedef _Float16 half4 __attribute__((ext_vector_type(4)));
typedef _Float16 half8 __attribute__((ext_vector_type(8)));
typedef _Float16 half2v __attribute__((ext_vector_type(2)));

__device__ __forceinline__ float lrelu(float x) { return x > 0.f ? x : 0.2f * x; }
__device__ __forceinline__ half2v bch2(float f) { return __builtin_bit_cast(half2v, f); }

// monotone float<->uint key for atomicMax on floats (handles negatives)
__device__ __forceinline__ unsigned fkey(float f) {
    unsigned b = __float_as_uint(f);
    return (b & 0x80000000u) ? ~b : (b | 0x80000000u);
}
__device__ __forceinline__ float funkey(unsigned k) {
    unsigned b = (k & 0x80000000u) ? (k & 0x7fffffffu) : ~k;
    return __uint_as_float(b);
}

// ---------------- CSR construction ----------------

__global__ void k_count(const int* __restrict__ dst, int* __restrict__ cnt,
                        int* __restrict__ pos) {
    int e = blockIdx.x * blockDim.x + threadIdx.x;
    if (e < NE) pos[e] = atomicAdd(&cnt[dst[e]], 1);
}

// pass 1 block sums; also zero pool/cnt_g/gmaxU and compute UV + W16T (weight-only work)
__global__ __launch_bounds__(256) void k_scan1(const int* __restrict__ cnt, int* __restrict__ bsum,
                                               float* __restrict__ pool, float* __restrict__ cnt_g,
                                               unsigned* __restrict__ gmaxU,
                                               const float* __restrict__ gat_W,
                                               const float* __restrict__ att_src,
                                               const float* __restrict__ att_dst,
                                               float* __restrict__ UV,
                                               _Float16* __restrict__ W16T) {
    __shared__ int buf[256];
    int gid = blockIdx.x * 256 + threadIdx.x;
    int v = (gid < NN) ? (cnt[gid] + 1) : 0;
    buf[threadIdx.x] = v;
    for (int j = gid; j < NGRAPH * 256; j += NBLK * 256) pool[j] = 0.f;
    if (gid < NGRAPH) cnt_g[gid] = 0.f;
    if (gid < 4) gmaxU[gid] = 0u;
    // fp16 transposed gat_W: W16T[c*64+f] = gat_W[f*256+c]
    for (int j = gid; j < 64 * 256; j += NBLK * 256) {
        int c = j >> 6, f = j & 63;
        W16T[j] = (_Float16)gat_W[f * 256 + c];
    }
    // folded attention vectors: UV[f*8+o], o<4 -> U (src) head o, o>=4 -> V (dst) head o-4
    if (gid < 512) {
        int f = gid >> 3, o = gid & 7, h = o & 3;
        const float* av = (o < 4) ? att_src : att_dst;
        float s = 0.f;
#pragma unroll 8
        for (int c = 0; c < 64; ++c) s += gat_W[f * 256 + h * 64 + c] * av[h * 64 + c];
        UV[gid] = s;
    }
    __syncthreads();
    for (int off = 128; off; off >>= 1) {
        if (threadIdx.x < off) buf[threadIdx.x] += buf[threadIdx.x + off];
        __syncthreads();
    }
    if (threadIdx.x == 0) bsum[blockIdx.x] = buf[0];
}

__global__ __launch_bounds__(256) void k_scan3(const int* __restrict__ cnt,
                                               const int* __restrict__ bsum,
                                               int* __restrict__ row_ptr,
                                               float* __restrict__ dinv,
                                               int* __restrict__ col) {
    __shared__ int sb[256];
    __shared__ int buf[256];
    int tid = threadIdx.x;
    int bv = (tid < NBLK) ? bsum[tid] : 0;
    sb[tid] = bv;
    __syncthreads();
    for (int off = 1; off < 256; off <<= 1) {
        int t = (tid >= off) ? sb[tid - off] : 0;
        __syncthreads();
        sb[tid] += t;
        __syncthreads();
    }
    int blockoff = (blockIdx.x == 0) ? 0 : sb[blockIdx.x - 1];
    int i = blockIdx.x * 256 + tid;
    int v = (i < NN) ? (cnt[i] + 1) : 0;
    buf[tid] = v;
    __syncthreads();
    for (int off = 1; off < 256; off <<= 1) {
        int t = (tid >= off) ? buf[tid - off] : 0;
        __syncthreads();
        buf[tid] += t;
        __syncthreads();
    }
    if (i < NN) {
        int rp = blockoff + buf[tid] - v;
        row_ptr[i] = rp;
        dinv[i] = rsqrtf((float)(cnt[i] + 1));
        col[rp] = i;   // self-loop occupies slot 0 of each row
    }
    if (i == 0) row_ptr[NN] = NEP;
}

__global__ void k_fill(const int* __restrict__ src, const int* __restrict__ dst,
                       const int* __restrict__ row_ptr, const int* __restrict__ pos,
                       int* __restrict__ col) {
    int idx = blockIdx.x * blockDim.x + threadIdx.x;
    if (idx < NE) {
        int d = dst[idx];
        col[row_ptr[d] + 1 + pos[idx]] = src[idx];
    }
}

// ---------------- GEMM: hxs16 = dinv .* (x @ gcn_W)  (row pre-scaled for GCN agg) ----------------

__global__ __launch_bounds__(256) void k_gemm64(const float* __restrict__ A,
                                                const float* __restrict__ B,
                                                const float* __restrict__ dinv,
                                                _Float16* __restrict__ C16, int n) {
    __shared__ float Bs[64 * 64];    // 16 KB
    __shared__ float As[64 * 68];    // 17 KB, stride 68
    int tid = threadIdx.x;
    int rb = blockIdx.x * 64;
    for (int i = tid; i < 1024; i += 256) ((float4*)Bs)[i] = ((const float4*)B)[i];
    for (int i = tid; i < 1024; i += 256) {
        int r = i >> 4, c = i & 15;
        int row = rb + r; if (row >= n) row = n - 1;
        ((float4*)As)[r * 17 + c] = ((const float4*)A)[(size_t)row * 16 + c];
    }
    __syncthreads();
    int lane = tid & 63, wv = tid >> 6;
    int fl = lane & 15, sub = lane >> 4;
    int r0 = wv * 16 + sub * 4;
    const float4* Bs4 = (const float4*)Bs;
    float4 acc0 = {0,0,0,0}, acc1 = {0,0,0,0}, acc2 = {0,0,0,0}, acc3 = {0,0,0,0};
#pragma unroll 4
    for (int k = 0; k < 64; ++k) {
        float4 b4 = Bs4[k * 16 + fl];
        float a0 = As[(r0 + 0) * 68 + k];
        float a1 = As[(r0 + 1) * 68 + k];
        float a2 = As[(r0 + 2) * 68 + k];
        float a3 = As[(r0 + 3) * 68 + k];
        acc0.x += a0 * b4.x; acc0.y += a0 * b4.y; acc0.z += a0 * b4.z; acc0.w += a0 * b4.w;
        acc1.x += a1 * b4.x; acc1.y += a1 * b4.y; acc1.z += a1 * b4.z; acc1.w += a1 * b4.w;
        acc2.x += a2 * b4.x; acc2.y += a2 * b4.y; acc2.z += a2 * b4.z; acc2.w += a2 * b4.w;
        acc3.x += a3 * b4.x; acc3.y += a3 * b4.y; acc3.z += a3 * b4.z; acc3.w += a3 * b4.w;
    }
    int row = rb + r0;
    float d0 = dinv[row + 0 < n ? row + 0 : n - 1];
    float d1 = dinv[row + 1 < n ? row + 1 : n - 1];
    float d2 = dinv[row + 2 < n ? row + 2 : n - 1];
    float d3 = dinv[row + 3 < n ? row + 3 : n - 1];
    half4 h0, h1, h2, h3;
    h0.x=(_Float16)(acc0.x*d0); h0.y=(_Float16)(acc0.y*d0); h0.z=(_Float16)(acc0.z*d0); h0.w=(_Float16)(acc0.w*d0);
    h1.x=(_Float16)(acc1.x*d1); h1.y=(_Float16)(acc1.y*d1); h1.z=(_Float16)(acc1.z*d1); h1.w=(_Float16)(acc1.w*d1);
    h2.x=(_Float16)(acc2.x*d2); h2.y=(_Float16)(acc2.y*d2); h2.z=(_Float16)(acc2.z*d2); h2.w=(_Float16)(acc2.w*d2);
    h3.x=(_Float16)(acc3.x*d3); h3.y=(_Float16)(acc3.y*d3); h3.z=(_Float16)(acc3.z*d3); h3.w=(_Float16)(acc3.w*d3);
    if (row + 0 < n) ((half4*)(C16 + (size_t)(row + 0) * 64))[fl] = h0;
    if (row + 1 < n) ((half4*)(C16 + (size_t)(row + 1) * 64))[fl] = h1;
    if (row + 2 < n) ((half4*)(C16 + (size_t)(row + 2) * 64))[fl] = h2;
    if (row + 3 < n) ((half4*)(C16 + (size_t)(row + 3) * 64))[fl] = h3;
}

// ---------------- GCN aggregation: 8 edge slots x 8 fl lanes, dwordx4 gathers ----------------
// Request-shape experiment: same bytes (128B/row), but 8 independent gather
// instructions per wave iteration base (16 with unroll-2) at 16B/lane.

__global__ __launch_bounds__(256) void k_gcn_agg(const _Float16* __restrict__ hxs16,
                                                 const int* __restrict__ row_ptr,
                                                 const int* __restrict__ col,
                                                 const float* __restrict__ dinv,
                                                 const float* __restrict__ bias,
                                                 const float* __restrict__ UV,
                                                 _Float16* __restrict__ h16,
                                                 float* __restrict__ a_s,
                                                 float* __restrict__ a_d) {
    int wid = (blockIdx.x * blockDim.x + threadIdx.x) >> 6;
    int lane = threadIdx.x & 63;
    if (wid >= NN) return;
    int slot = lane >> 3;   // edge slot 0..7 (also UV column for logits)
    int fl   = lane & 7;    // half8 index within 64-feat row
    int s0 = row_ptr[wid], s1 = row_ptr[wid + 1];
    float di = dinv[wid];
    const half8* hx8 = (const half8*)hxs16;   // row stride = 8 half8 (128B)
    float a0 = 0.f, a1 = 0.f, a2 = 0.f, a3 = 0.f;
    float a4 = 0.f, a5 = 0.f, a6 = 0.f, a7 = 0.f;
    int k = s0 + slot;
    // 16 edges in flight per wave iteration (8 slots x unroll-2), 16B per lane
    for (; k + 8 < s1; k += 16) {
        int i0 = col[k], i1 = col[k + 8];
        half8 v0 = hx8[(size_t)i0 * 8 + fl];
        half8 v1 = hx8[(size_t)i1 * 8 + fl];
        a0 += (float)v0[0] + (float)v1[0];
        a1 += (float)v0[1] + (float)v1[1];
        a2 += (float)v0[2] + (float)v1[2];
        a3 += (float)v0[3] + (float)v1[3];
        a4 += (float)v0[4] + (float)v1[4];
        a5 += (float)v0[5] + (float)v1[5];
        a6 += (float)v0[6] + (float)v1[6];
        a7 += (float)v0[7] + (float)v1[7];
    }
    for (; k < s1; k += 8) {
        half8 v = hx8[(size_t)col[k] * 8 + fl];
        a0 += (float)v[0]; a1 += (float)v[1];
        a2 += (float)v[2]; a3 += (float)v[3];
        a4 += (float)v[4]; a5 += (float)v[5];
        a6 += (float)v[6]; a7 += (float)v[7];
    }
    // reduce over the 8 slots (lane bits 3,4,5)
#define RED8(x) x += __shfl_xor(x, 8); x += __shfl_xor(x, 16); x += __shfl_xor(x, 32);
    RED8(a0) RED8(a1) RED8(a2) RED8(a3) RED8(a4) RED8(a5) RED8(a6) RED8(a7)
#undef RED8
    // all lanes hold full sums for feature group fl; dst-side scale + bias + relu
    float4 bbA = ((const float4*)bias)[2 * fl];
    float4 bbB = ((const float4*)bias)[2 * fl + 1];
    float z0 = fmaxf(a0 * di + bbA.x, 0.f);
    float z1 = fmaxf(a1 * di + bbA.y, 0.f);
    float z2 = fmaxf(a2 * di + bbA.z, 0.f);
    float z3 = fmaxf(a3 * di + bbA.w, 0.f);
    float z4 = fmaxf(a4 * di + bbB.x, 0.f);
    float z5 = fmaxf(a5 * di + bbB.y, 0.f);
    float z6 = fmaxf(a6 * di + bbB.z, 0.f);
    float z7 = fmaxf(a7 * di + bbB.w, 0.f);
    if (slot == 0) {
        half8 z;
        z[0] = (_Float16)z0; z[1] = (_Float16)z1; z[2] = (_Float16)z2; z[3] = (_Float16)z3;
        z[4] = (_Float16)z4; z[5] = (_Float16)z5; z[6] = (_Float16)z6; z[7] = (_Float16)z7;
        ((half8*)(h16 + (size_t)wid * 64))[fl] = z;
    }
    // fused attention logits: slot o computes UV column o (o<4 -> ps head o, o>=4 -> pd head o-4)
    int f0 = fl * 8;
    float val = z0 * UV[(f0 + 0) * 8 + slot] + z1 * UV[(f0 + 1) * 8 + slot]
              + z2 * UV[(f0 + 2) * 8 + slot] + z3 * UV[(f0 + 3) * 8 + slot]
              + z4 * UV[(f0 + 4) * 8 + slot] + z5 * UV[(f0 + 5) * 8 + slot]
              + z6 * UV[(f0 + 6) * 8 + slot] + z7 * UV[(f0 + 7) * 8 + slot];
    val += __shfl_xor(val, 1);
    val += __shfl_xor(val, 2);
    val += __shfl_xor(val, 4);
    if (fl == 0) {
        if (slot < 4) a_s[wid * 4 + slot] = val;
        else          a_d[wid * 4 + (slot - 4)] = val;
    }
}

// ---------------- global per-head max of a_s (safe softmax bound) ----------------

__global__ __launch_bounds__(256) void k_gmax(const float* __restrict__ a_s,
                                              unsigned* __restrict__ gmaxU) {
    __shared__ unsigned sm[4];
    int tid = threadIdx.x;
    if (tid < 4) sm[tid] = 0u;
    __syncthreads();
    float mx = -1e30f, my = -1e30f, mz = -1e30f, mw = -1e30f;
    int stride = gridDim.x * 256;
    for (int n = blockIdx.x * 256 + tid; n < NN; n += stride) {
        float4 v = ((const float4*)a_s)[n];
        mx = fmaxf(mx, v.x); my = fmaxf(my, v.y);
        mz = fmaxf(mz, v.z); mw = fmaxf(mw, v.w);
    }
    atomicMax(&sm[0], fkey(mx)); atomicMax(&sm[1], fkey(my));
    atomicMax(&sm[2], fkey(mz)); atomicMax(&sm[3], fkey(mw));
    __syncthreads();
    if (tid < 4) atomicMax(&gmaxU[tid], sm[tid]);
}

// ---------------- GAT aggregation: each h row loaded ONCE; 4 edge slots x 16 fl lanes ----------------

__global__ __launch_bounds__(256) void k_gat_h(const _Float16* __restrict__ h16,
                                               const float* __restrict__ a_s,
                                               const float* __restrict__ a_d,
                                               const int* __restrict__ row_ptr,
                                               const int* __restrict__ col,
                                               const unsigned* __restrict__ gmaxU,
                                               _Float16* __restrict__ aggH) {
    int tid = threadIdx.x;
    int wv = tid >> 6, lane = tid & 63;
    int wid = blockIdx.x * 4 + wv;           // NN == gridDim.x*4, always valid
    int slot = lane >> 4;                    // edge slot
    int fl = lane & 15;                      // half4 index within 64-feat h row

    int s0 = row_ptr[wid], s1 = row_ptr[wid + 1];
    float4 ad4 = ((const float4*)a_d)[wid];
    float M0 = lrelu(funkey(gmaxU[0]) + ad4.x);
    float M1 = lrelu(funkey(gmaxU[1]) + ad4.y);
    float M2 = lrelu(funkey(gmaxU[2]) + ad4.z);
    float M3 = lrelu(funkey(gmaxU[3]) + ad4.w);
    const half4* h4 = (const half4*)h16;
    const float4* as4 = (const float4*)a_s;

    float t0 = 1e-30f, t1 = 1e-30f, t2 = 1e-30f, t3 = 1e-30f;
    float4 A0 = {0,0,0,0}, A1 = {0,0,0,0}, A2 = {0,0,0,0}, A3 = {0,0,0,0};

    int k = s0 + slot;
    for (; k + 4 < s1; k += 8) {
        int ia = col[k], ib = col[k + 4];
        float4 ea = as4[ia];
        float4 eb = as4[ib];
        half4 va = h4[(size_t)ia * 16 + fl];
        half4 vb = h4[(size_t)ib * 16 + fl];
        float wa0 = __expf(lrelu(ea.x + ad4.x) - M0);
        float wa1 = __expf(lrelu(ea.y + ad4.y) - M1);
        float wa2 = __expf(lrelu(ea.z + ad4.z) - M2);
        float wa3 = __expf(lrelu(ea.w + ad4.w) - M3);
        float wb0 = __expf(lrelu(eb.x + ad4.x) - M0);
        float wb1 = __expf(lrelu(eb.y + ad4.y) - M1);
        float wb2 = __expf(lrelu(eb.z + ad4.z) - M2);
        float wb3 = __expf(lrelu(eb.w + ad4.w) - M3);
        t0 += wa0 + wb0; t1 += wa1 + wb1; t2 += wa2 + wb2; t3 += wa3 + wb3;
        float vax = (float)va.x, vay = (float)va.y, vaz = (float)va.z, vaw = (float)va.w;
        float vbx = (float)vb.x, vby = (float)vb.y, vbz = (float)vb.z, vbw = (float)vb.w;
        A0.x += wa0 * vax + wb0 * vbx; A0.y += wa0 * vay + wb0 * vby;
        A0.z += wa0 * vaz + wb0 * vbz; A0.w += wa0 * vaw + wb0 * vbw;
        A1.x += wa1 * vax + wb1 * vbx; A1.y += wa1 * vay + wb1 * vby;
        A1.z += wa1 * vaz + wb1 * vbz; A1.w += wa1 * vaw + wb1 * vbw;
        A2.x += wa2 * vax + wb2 * vbx; A2.y += wa2 * vay + wb2 * vby;
        A2.z += wa2 * vaz + wb2 * vbz; A2.w += wa2 * vaw + wb2 * vbw;
        A3.x += wa3 * vax + wb3 * vbx; A3.y += wa3 * vay + wb3 * vby;
        A3.z += wa3 * vaz + wb3 * vbz; A3.w += wa3 * vaw + wb3 * vbw;
    }
    if (k < s1) {
        int ia = col[k];
        float4 ea = as4[ia];
        half4 va = h4[(size_t)ia * 16 + fl];
        float wa0 = __expf(lrelu(ea.x + ad4.x) - M0);
        float wa1 = __expf(lrelu(ea.y + ad4.y) - M1);
        float wa2 = __expf(lrelu(ea.z + ad4.z) - M2);
        float wa3 = __expf(lrelu(ea.w + ad4.w) - M3);
        t0 += wa0; t1 += wa1; t2 += wa2; t3 += wa3;
        float vax = (float)va.x, vay = (float)va.y, vaz = (float)va.z, vaw = (float)va.w;
        A0.x += wa0 * vax; A0.y += wa0 * vay; A0.z += wa0 * vaz; A0.w += wa0 * vaw;
        A1.x += wa1 * vax; A1.y += wa1 * vay; A1.z += wa1 * vaz; A1.w += wa1 * vaw;
        A2.x += wa2 * vax; A2.y += wa2 * vay; A2.z += wa2 * vaz; A2.w += wa2 * vaw;
        A3.x += wa3 * vax; A3.y += wa3 * vay; A3.z += wa3 * vaz; A3.w += wa3 * vaw;
    }
    // cross-slot reduction (values replicated over the 16 fl lanes of each slot)
#define REDX(x) x += __shfl_xor(x, 16); x += __shfl_xor(x, 32);
    REDX(t0) REDX(t1) REDX(t2) REDX(t3)
    REDX(A0.x) REDX(A0.y) REDX(A0.z) REDX(A0.w)
    REDX(A1.x) REDX(A1.y) REDX(A1.z) REDX(A1.w)
    REDX(A2.x) REDX(A2.y) REDX(A2.z) REDX(A2.w)
    REDX(A3.x) REDX(A3.y) REDX(A3.z) REDX(A3.w)
#undef REDX
    // slot s stores head s at its fl: address = wid*256 + slot*64 + fl*4 = wid*256 + lane*4
    float rsel = slot == 0 ? t0 : slot == 1 ? t1 : slot == 2 ? t2 : t3;
    float4 Asel = slot == 0 ? A0 : slot == 1 ? A1 : slot == 2 ? A2 : A3;
    float r = 1.f / rsel;
    half4 o;
    o.x = (_Float16)(Asel.x * r); o.y = (_Float16)(Asel.y * r);
    o.z = (_Float16)(Asel.z * r); o.w = (_Float16)(Asel.w * r);
    ((half4*)(aggH + (size_t)wid * 256))[lane] = o;
}

// ---------------- deferred projection, register-resident W column, fused pooling ----------------

__global__ __launch_bounds__(256) void k_post2(const _Float16* __restrict__ aggH,
                                               const _Float16* __restrict__ W16T,
                                               const float* __restrict__ gat_b,
                                               const int* __restrict__ batch,
                                               float* __restrict__ pool,
                                               float* __restrict__ cnt_g) {
    int tid = threadIdx.x;
    int lane = tid & 63;
    int wv = __builtin_amdgcn_readfirstlane(tid >> 6);
    int h = blockIdx.y;
    int c = h * 64 + lane;                    // global output column
    const float4* wp = (const float4*)(W16T + (size_t)c * 64);
    float4 Wb[8];
#pragma unroll
    for (int i = 0; i < 8; ++i) Wb[i] = wp[i];
    float gb = gat_b[c];

    int rbeg = (blockIdx.x * 4 + wv) * 32;
    int rend = rbeg + 32; if (rend > NN) rend = NN;

    float psum = 0.f;
    int curb = -1, rcnt = 0;
#pragma unroll 2
    for (int row = rbeg; row < rend; ++row) {
        int b = batch[row];
        if (b != curb) {
            if (curb >= 0) {
                atomicAdd(&pool[(size_t)curb * 256 + c], psum);
                if (h == 0 && lane == 0) atomicAdd(&cnt_g[curb], (float)rcnt);
            }
            psum = 0.f; rcnt = 0; curb = b;
        }
        const float4* ap = (const float4*)(aggH + (size_t)row * 256 + h * 64);
        float4 Ab[8];
#pragma unroll
        for (int i = 0; i < 8; ++i) Ab[i] = ap[i];
        float ac0 = 0.f, ac1 = 0.f, ac2 = 0.f, ac3 = 0.f;
#pragma unroll
        for (int i = 0; i < 8; ++i) {
            ac0 = __builtin_amdgcn_fdot2(bch2(Ab[i].x), bch2(Wb[i].x), ac0, false);
            ac1 = __builtin_amdgcn_fdot2(bch2(Ab[i].y), bch2(Wb[i].y), ac1, false);
            ac2 = __builtin_amdgcn_fdot2(bch2(Ab[i].z), bch2(Wb[i].z), ac2, false);
            ac3 = __builtin_amdgcn_fdot2(bch2(Ab[i].w), bch2(Wb[i].w), ac3, false);
        }
        float acc = (ac0 + ac1) + (ac2 + ac3);
        psum += fmaxf(acc + gb, 0.f);
        ++rcnt;
    }
    if (curb >= 0) {
        atomicAdd(&pool[(size_t)curb * 256 + c], psum);
        if (h == 0 && lane == 0) atomicAdd(&cnt_g[curb], (float)rcnt);
    }
}

// ---------------- output projection ----------------

__global__ void k_out(const float* __restrict__ pool, const float* __restrict__ cnt_g,
                      const float* __restrict__ W, const float* __restrict__ b,
                      float* __restrict__ out) {
    int idx = blockIdx.x * blockDim.x + threadIdx.x;
    if (idx >= NGRAPH * NOUT) return;
    int gg = idx >> 5, o = idx & 31;
    float c = cnt_g[gg];
    c = c > 1.f ? c : 1.f;
    float rinv = 1.f / c;
    const float* p = pool + (size_t)gg * 256;
    float acc = 0.f;
#pragma unroll 8
    for (int f = 0; f < 256; ++f) acc += p[f] * W[f * 32 + o];
    out[idx] = acc * rinv + b[o];
}

// ---------------- launch ----------------

extern "C" void kernel_launch(void* const* d_in, const int* in_sizes, int n_in,
                              void* d_out, int out_size, void* d_ws, size_t ws_size,
                              hipStream_t stream) {
    const float* x       = (const float*)d_in[0];
    const int*   eidx    = (const int*)d_in[1];
    const int*   batch   = (const int*)d_in[2];
    const float* gcn_W   = (const float*)d_in[3];
    const float* gcn_b   = (const float*)d_in[4];
    const float* gat_W   = (const float*)d_in[5];
    const float* att_src = (const float*)d_in[6];
    const float* att_dst = (const float*)d_in[7];
    const float* gat_b   = (const float*)d_in[8];
    const float* out_W   = (const float*)d_in[9];
    const float* out_b   = (const float*)d_in[10];
    float* out = (float*)d_out;

    const int* src = eidx;        // edge_index[0]
    const int* dst = eidx + NE;   // edge_index[1]

    size_t off = 0;
    auto carve = [&](size_t bytes) -> char* {
        char* p = (char*)d_ws + off;
        off += (bytes + 255) & ~(size_t)255;
        return p;
    };
    int*      cnt     = (int*)carve(NN * sizeof(int));
    int*      pos     = (int*)carve((size_t)NE * sizeof(int));
    int*      row_ptr = (int*)carve((NN + 1) * sizeof(int));
    int*      bsum    = (int*)carve(256 * sizeof(int));
    int*      colb    = (int*)carve((size_t)NEP * sizeof(int));
    float*    dinv    = (float*)carve(NN * sizeof(float));
    _Float16* hx16    = (_Float16*)carve((size_t)NN * 64 * sizeof(_Float16));
    _Float16* h16     = (_Float16*)carve((size_t)NN * 64 * sizeof(_Float16));
    _Float16* aggH16  = (_Float16*)carve((size_t)NN * 256 * sizeof(_Float16));
    float*    a_s     = (float*)carve((size_t)NN * 4 * sizeof(float));
    float*    a_d     = (float*)carve((size_t)NN * 4 * sizeof(float));
    float*    UV      = (float*)carve(64 * 8 * sizeof(float));
    _Float16* W16T    = (_Float16*)carve(64 * 256 * sizeof(_Float16));
    unsigned* gmaxU   = (unsigned*)carve(4 * sizeof(unsigned));
    float*    pool    = (float*)carve((size_t)NGRAPH * 256 * sizeof(float));
    float*    cnt_g   = (float*)carve(NGRAPH * sizeof(float));

    hipMemsetAsync(cnt, 0, NN * sizeof(int), stream);

    // CSR build (+ weight-side precompute folded into k_scan1)
    k_count<<<(NE + 255) / 256, 256, 0, stream>>>(dst, cnt, pos);
    k_scan1<<<NBLK, 256, 0, stream>>>(cnt, bsum, pool, cnt_g, gmaxU,
                                      gat_W, att_src, att_dst, UV, W16T);
    k_scan3<<<NBLK, 256, 0, stream>>>(cnt, bsum, row_ptr, dinv, colb);
    k_fill<<<(NE + 255) / 256, 256, 0, stream>>>(src, dst, row_ptr, pos, colb);

    // GCN (hx rows pre-scaled by dinv -> agg is pure gather+add; 8-slot dwordx4 gathers)
    k_gemm64<<<(NN + 63) / 64, 256, 0, stream>>>(x, gcn_W, dinv, hx16, NN);
    k_gcn_agg<<<(NN * 64 + 255) / 256, 256, 0, stream>>>(hx16, row_ptr, colb, dinv, gcn_b,
                                                         UV, h16, a_s, a_d);

    // safe softmax bound, then GAT aggregation over h (128B/edge gather, loaded once)
    k_gmax<<<128, 256, 0, stream>>>(a_s, gmaxU);
    k_gat_h<<<NN / 4, 256, 0, stream>>>(h16, a_s, a_d, row_ptr, colb, gmaxU, aggH16);

    // deferred projection + bias + relu + fused register pooling
    k_post2<<<dim3(391, 4), 256, 0, stream>>>(aggH16, W16T, gat_b, batch, pool, cnt_g);

    // output projection
    k_out<<<(NGRAPH * NOUT + 255) / 256, 256, 0, stream>>>(pool, cnt_g, out_W, out_b, out);
}

// Round 11
// 284.376 us; speedup vs baseline: 1.2163x; 1.0184x over previous
//
#include <hip/hip_runtime.h>
#include <math.h>

#define NN 50000
#define NE 800000
#define NEP (NE + NN)   // edges incl self-loops
#define NGRAPH 500
#define NOUT 32
#define NBLK 196        // ceil(NN/256)

typedef _Float16 half4 __attribute__((ext_vector_type(4)));
typedef _Float16 half8 __attribute__((ext_vector_type(8)));
typedef _Float16 half2v __attribute__((ext_vector_type(2)));

__device__ __forceinline__ float lrelu(float x) { return x > 0.f ? x : 0.2f * x; }
__device__ __forceinline__ half2v bch2(float f) { return __builtin_bit_cast(half2v, f); }

// monotone float<->uint key for atomicMax on floats (handles negatives)
__device__ __forceinline__ unsigned fkey(float f) {
    unsigned b = __float_as_uint(f);
    return (b & 0x80000000u) ? ~b : (b | 0x80000000u);
}
__device__ __forceinline__ float funkey(unsigned k) {
    unsigned b = (k & 0x80000000u) ? (k & 0x7fffffffu) : ~k;
    return __uint_as_float(b);
}

// ---------------- CSR construction ----------------

__global__ void k_count(const int* __restrict__ dst, int* __restrict__ cnt,
                        int* __restrict__ pos) {
    int e = blockIdx.x * blockDim.x + threadIdx.x;
    if (e < NE) pos[e] = atomicAdd(&cnt[dst[e]], 1);
}

// pass 1 block sums; also zero pool/cnt_g/gmaxU and compute UV + W16T (weight-only work)
__global__ __launch_bounds__(256) void k_scan1(const int* __restrict__ cnt, int* __restrict__ bsum,
                                               float* __restrict__ pool, float* __restrict__ cnt_g,
                                               unsigned* __restrict__ gmaxU,
                                               const float* __restrict__ gat_W,
                                               const float* __restrict__ att_src,
                                               const float* __restrict__ att_dst,
                                               float* __restrict__ UV,
                                               _Float16* __restrict__ W16T) {
    __shared__ int buf[256];
    int gid = blockIdx.x * 256 + threadIdx.x;
    int v = (gid < NN) ? (cnt[gid] + 1) : 0;
    buf[threadIdx.x] = v;
    for (int j = gid; j < NGRAPH * 256; j += NBLK * 256) pool[j] = 0.f;
    if (gid < NGRAPH) cnt_g[gid] = 0.f;
    if (gid < 4) gmaxU[gid] = 0u;
    // fp16 transposed gat_W: W16T[c*64+f] = gat_W[f*256+c]
    for (int j = gid; j < 64 * 256; j += NBLK * 256) {
        int c = j >> 6, f = j & 63;
        W16T[j] = (_Float16)gat_W[f * 256 + c];
    }
    // folded attention vectors: UV[f*8+o], o<4 -> U (src) head o, o>=4 -> V (dst) head o-4
    if (gid < 512) {
        int f = gid >> 3, o = gid & 7, h = o & 3;
        const float* av = (o < 4) ? att_src : att_dst;
        float s = 0.f;
#pragma unroll 8
        for (int c = 0; c < 64; ++c) s += gat_W[f * 256 + h * 64 + c] * av[h * 64 + c];
        UV[gid] = s;
    }
    __syncthreads();
    for (int off = 128; off; off >>= 1) {
        if (threadIdx.x < off) buf[threadIdx.x] += buf[threadIdx.x + off];
        __syncthreads();
    }
    if (threadIdx.x == 0) bsum[blockIdx.x] = buf[0];
}

__global__ __launch_bounds__(256) void k_scan3(const int* __restrict__ cnt,
                                               const int* __restrict__ bsum,
                                               int* __restrict__ row_ptr,
                                               float* __restrict__ dinv,
                                               int* __restrict__ col) {
    __shared__ int sb[256];
    __shared__ int buf[256];
    int tid = threadIdx.x;
    int bv = (tid < NBLK) ? bsum[tid] : 0;
    sb[tid] = bv;
    __syncthreads();
    for (int off = 1; off < 256; off <<= 1) {
        int t = (tid >= off) ? sb[tid - off] : 0;
        __syncthreads();
        sb[tid] += t;
        __syncthreads();
    }
    int blockoff = (blockIdx.x == 0) ? 0 : sb[blockIdx.x - 1];
    int i = blockIdx.x * 256 + tid;
    int v = (i < NN) ? (cnt[i] + 1) : 0;
    buf[tid] = v;
    __syncthreads();
    for (int off = 1; off < 256; off <<= 1) {
        int t = (tid >= off) ? buf[tid - off] : 0;
        __syncthreads();
        buf[tid] += t;
        __syncthreads();
    }
    if (i < NN) {
        int rp = blockoff + buf[tid] - v;
        row_ptr[i] = rp;
        dinv[i] = rsqrtf((float)(cnt[i] + 1));
        col[rp] = i;   // self-loop occupies slot 0 of each row
    }
    if (i == 0) row_ptr[NN] = NEP;
}

__global__ void k_fill(const int* __restrict__ src, const int* __restrict__ dst,
                       const int* __restrict__ row_ptr, const int* __restrict__ pos,
                       int* __restrict__ col) {
    int idx = blockIdx.x * blockDim.x + threadIdx.x;
    if (idx < NE) {
        int d = dst[idx];
        col[row_ptr[d] + 1 + pos[idx]] = src[idx];
    }
}

// ---------------- GEMM: hxs16 = dinv .* (x @ gcn_W)  (row pre-scaled for GCN agg) ----------------

__global__ __launch_bounds__(256) void k_gemm64(const float* __restrict__ A,
                                                const float* __restrict__ B,
                                                const float* __restrict__ dinv,
                                                _Float16* __restrict__ C16, int n) {
    __shared__ float Bs[64 * 64];    // 16 KB
    __shared__ float As[64 * 68];    // 17 KB, stride 68
    int tid = threadIdx.x;
    int rb = blockIdx.x * 64;
    for (int i = tid; i < 1024; i += 256) ((float4*)Bs)[i] = ((const float4*)B)[i];
    for (int i = tid; i < 1024; i += 256) {
        int r = i >> 4, c = i & 15;
        int row = rb + r; if (row >= n) row = n - 1;
        ((float4*)As)[r * 17 + c] = ((const float4*)A)[(size_t)row * 16 + c];
    }
    __syncthreads();
    int lane = tid & 63, wv = tid >> 6;
    int fl = lane & 15, sub = lane >> 4;
    int r0 = wv * 16 + sub * 4;
    const float4* Bs4 = (const float4*)Bs;
    float4 acc0 = {0,0,0,0}, acc1 = {0,0,0,0}, acc2 = {0,0,0,0}, acc3 = {0,0,0,0};
#pragma unroll 4
    for (int k = 0; k < 64; ++k) {
        float4 b4 = Bs4[k * 16 + fl];
        float a0 = As[(r0 + 0) * 68 + k];
        float a1 = As[(r0 + 1) * 68 + k];
        float a2 = As[(r0 + 2) * 68 + k];
        float a3 = As[(r0 + 3) * 68 + k];
        acc0.x += a0 * b4.x; acc0.y += a0 * b4.y; acc0.z += a0 * b4.z; acc0.w += a0 * b4.w;
        acc1.x += a1 * b4.x; acc1.y += a1 * b4.y; acc1.z += a1 * b4.z; acc1.w += a1 * b4.w;
        acc2.x += a2 * b4.x; acc2.y += a2 * b4.y; acc2.z += a2 * b4.z; acc2.w += a2 * b4.w;
        acc3.x += a3 * b4.x; acc3.y += a3 * b4.y; acc3.z += a3 * b4.z; acc3.w += a3 * b4.w;
    }
    int row = rb + r0;
    float d0 = dinv[row + 0 < n ? row + 0 : n - 1];
    float d1 = dinv[row + 1 < n ? row + 1 : n - 1];
    float d2 = dinv[row + 2 < n ? row + 2 : n - 1];
    float d3 = dinv[row + 3 < n ? row + 3 : n - 1];
    half4 h0, h1, h2, h3;
    h0.x=(_Float16)(acc0.x*d0); h0.y=(_Float16)(acc0.y*d0); h0.z=(_Float16)(acc0.z*d0); h0.w=(_Float16)(acc0.w*d0);
    h1.x=(_Float16)(acc1.x*d1); h1.y=(_Float16)(acc1.y*d1); h1.z=(_Float16)(acc1.z*d1); h1.w=(_Float16)(acc1.w*d1);
    h2.x=(_Float16)(acc2.x*d2); h2.y=(_Float16)(acc2.y*d2); h2.z=(_Float16)(acc2.z*d2); h2.w=(_Float16)(acc2.w*d2);
    h3.x=(_Float16)(acc3.x*d3); h3.y=(_Float16)(acc3.y*d3); h3.z=(_Float16)(acc3.z*d3); h3.w=(_Float16)(acc3.w*d3);
    if (row + 0 < n) ((half4*)(C16 + (size_t)(row + 0) * 64))[fl] = h0;
    if (row + 1 < n) ((half4*)(C16 + (size_t)(row + 1) * 64))[fl] = h1;
    if (row + 2 < n) ((half4*)(C16 + (size_t)(row + 2) * 64))[fl] = h2;
    if (row + 3 < n) ((half4*)(C16 + (size_t)(row + 3) * 64))[fl] = h3;
}

// ---------------- GCN aggregation: 8 edge slots x 8 fl lanes, dwordx4 gathers ----------------

__global__ __launch_bounds__(256) void k_gcn_agg(const _Float16* __restrict__ hxs16,
                                                 const int* __restrict__ row_ptr,
                                                 const int* __restrict__ col,
                                                 const float* __restrict__ dinv,
                                                 const float* __restrict__ bias,
                                                 const float* __restrict__ UV,
                                                 _Float16* __restrict__ h16,
                                                 float* __restrict__ a_s,
                                                 float* __restrict__ a_d) {
    int wid = (blockIdx.x * blockDim.x + threadIdx.x) >> 6;
    int lane = threadIdx.x & 63;
    if (wid >= NN) return;
    int slot = lane >> 3;   // edge slot 0..7 (also UV column for logits)
    int fl   = lane & 7;    // half8 index within 64-feat row
    int s0 = row_ptr[wid], s1 = row_ptr[wid + 1];
    float di = dinv[wid];
    const half8* hx8 = (const half8*)hxs16;   // row stride = 8 half8 (128B)
    float a0 = 0.f, a1 = 0.f, a2 = 0.f, a3 = 0.f;
    float a4 = 0.f, a5 = 0.f, a6 = 0.f, a7 = 0.f;
    int k = s0 + slot;
    // 16 edges in flight per wave iteration (8 slots x unroll-2), 16B per lane
    for (; k + 8 < s1; k += 16) {
        int i0 = col[k], i1 = col[k + 8];
        half8 v0 = hx8[(size_t)i0 * 8 + fl];
        half8 v1 = hx8[(size_t)i1 * 8 + fl];
        a0 += (float)v0[0] + (float)v1[0];
        a1 += (float)v0[1] + (float)v1[1];
        a2 += (float)v0[2] + (float)v1[2];
        a3 += (float)v0[3] + (float)v1[3];
        a4 += (float)v0[4] + (float)v1[4];
        a5 += (float)v0[5] + (float)v1[5];
        a6 += (float)v0[6] + (float)v1[6];
        a7 += (float)v0[7] + (float)v1[7];
    }
    for (; k < s1; k += 8) {
        half8 v = hx8[(size_t)col[k] * 8 + fl];
        a0 += (float)v[0]; a1 += (float)v[1];
        a2 += (float)v[2]; a3 += (float)v[3];
        a4 += (float)v[4]; a5 += (float)v[5];
        a6 += (float)v[6]; a7 += (float)v[7];
    }
    // reduce over the 8 slots (lane bits 3,4,5)
#define RED8(x) x += __shfl_xor(x, 8); x += __shfl_xor(x, 16); x += __shfl_xor(x, 32);
    RED8(a0) RED8(a1) RED8(a2) RED8(a3) RED8(a4) RED8(a5) RED8(a6) RED8(a7)
#undef RED8
    // all lanes hold full sums for feature group fl; dst-side scale + bias + relu
    float4 bbA = ((const float4*)bias)[2 * fl];
    float4 bbB = ((const float4*)bias)[2 * fl + 1];
    float z0 = fmaxf(a0 * di + bbA.x, 0.f);
    float z1 = fmaxf(a1 * di + bbA.y, 0.f);
    float z2 = fmaxf(a2 * di + bbA.z, 0.f);
    float z3 = fmaxf(a3 * di + bbA.w, 0.f);
    float z4 = fmaxf(a4 * di + bbB.x, 0.f);
    float z5 = fmaxf(a5 * di + bbB.y, 0.f);
    float z6 = fmaxf(a6 * di + bbB.z, 0.f);
    float z7 = fmaxf(a7 * di + bbB.w, 0.f);
    if (slot == 0) {
        half8 z;
        z[0] = (_Float16)z0; z[1] = (_Float16)z1; z[2] = (_Float16)z2; z[3] = (_Float16)z3;
        z[4] = (_Float16)z4; z[5] = (_Float16)z5; z[6] = (_Float16)z6; z[7] = (_Float16)z7;
        ((half8*)(h16 + (size_t)wid * 64))[fl] = z;
    }
    // fused attention logits: slot o computes UV column o (o<4 -> ps head o, o>=4 -> pd head o-4)
    int f0 = fl * 8;
    float val = z0 * UV[(f0 + 0) * 8 + slot] + z1 * UV[(f0 + 1) * 8 + slot]
              + z2 * UV[(f0 + 2) * 8 + slot] + z3 * UV[(f0 + 3) * 8 + slot]
              + z4 * UV[(f0 + 4) * 8 + slot] + z5 * UV[(f0 + 5) * 8 + slot]
              + z6 * UV[(f0 + 6) * 8 + slot] + z7 * UV[(f0 + 7) * 8 + slot];
    val += __shfl_xor(val, 1);
    val += __shfl_xor(val, 2);
    val += __shfl_xor(val, 4);
    if (fl == 0) {
        if (slot < 4) a_s[wid * 4 + slot] = val;
        else          a_d[wid * 4 + (slot - 4)] = val;
    }
}

// ---------------- global per-head max of a_s (safe softmax bound) ----------------

__global__ __launch_bounds__(256) void k_gmax(const float* __restrict__ a_s,
                                              unsigned* __restrict__ gmaxU) {
    __shared__ unsigned sm[4];
    int tid = threadIdx.x;
    if (tid < 4) sm[tid] = 0u;
    __syncthreads();
    float mx = -1e30f, my = -1e30f, mz = -1e30f, mw = -1e30f;
    int stride = gridDim.x * 256;
    for (int n = blockIdx.x * 256 + tid; n < NN; n += stride) {
        float4 v = ((const float4*)a_s)[n];
        mx = fmaxf(mx, v.x); my = fmaxf(my, v.y);
        mz = fmaxf(mz, v.z); mw = fmaxf(mw, v.w);
    }
    atomicMax(&sm[0], fkey(mx)); atomicMax(&sm[1], fkey(my));
    atomicMax(&sm[2], fkey(mz)); atomicMax(&sm[3], fkey(mw));
    __syncthreads();
    if (tid < 4) atomicMax(&gmaxU[tid], sm[tid]);
}

// ---------------- GAT aggregation: head-owned lanes ----------------
// lane = grp*32 + head*8 + fl:  grp in {0,1} stripes edges by parity,
// head = (lane>>3)&3 owns ONE head's weights (1 expf/edge per 32-lane group),
// fl covers 8 feats via half8. acc = 9 regs; epilogue = single xor-32 reduce.

__global__ __launch_bounds__(256) void k_gat_h(const _Float16* __restrict__ h16,
                                               const float* __restrict__ a_s,
                                               const float* __restrict__ a_d,
                                               const int* __restrict__ row_ptr,
                                               const int* __restrict__ col,
                                               const unsigned* __restrict__ gmaxU,
                                               _Float16* __restrict__ aggH) {
    int tid = threadIdx.x;
    int wv = tid >> 6, lane = tid & 63;
    int wid = blockIdx.x * 4 + wv;           // NN == gridDim.x*4, always valid
    int grp  = lane >> 5;                    // edge-parity group
    int head = (lane >> 3) & 3;              // owned head
    int fl   = lane & 7;                     // half8 index within 64-feat h row

    int s0 = row_ptr[wid], s1 = row_ptr[wid + 1];
    float adh = a_d[wid * 4 + head];
    float Mh = lrelu(funkey(gmaxU[head]) + adh);   // e <= Mh for every edge of this node/head
    const half8* h8 = (const half8*)h16;           // row stride = 8 half8 (128B)

    float t = 1e-30f;
    float c0 = 0.f, c1 = 0.f, c2 = 0.f, c3 = 0.f;
    float c4 = 0.f, c5 = 0.f, c6 = 0.f, c7 = 0.f;

    int k = s0 + grp;
    // unroll-4: this lane handles edges k, k+2, k+4, k+6 (8 edges in flight per wave)
    for (; k + 6 < s1; k += 8) {
        int i0 = col[k], i1 = col[k + 2], i2 = col[k + 4], i3 = col[k + 6];
        float e0 = a_s[i0 * 4 + head];
        float e1 = a_s[i1 * 4 + head];
        float e2 = a_s[i2 * 4 + head];
        float e3 = a_s[i3 * 4 + head];
        half8 v0 = h8[(size_t)i0 * 8 + fl];
        half8 v1 = h8[(size_t)i1 * 8 + fl];
        half8 v2 = h8[(size_t)i2 * 8 + fl];
        half8 v3 = h8[(size_t)i3 * 8 + fl];
        float w0 = __expf(lrelu(e0 + adh) - Mh);
        float w1 = __expf(lrelu(e1 + adh) - Mh);
        float w2 = __expf(lrelu(e2 + adh) - Mh);
        float w3 = __expf(lrelu(e3 + adh) - Mh);
        t += (w0 + w1) + (w2 + w3);
        c0 += w0 * (float)v0[0] + w1 * (float)v1[0] + w2 * (float)v2[0] + w3 * (float)v3[0];
        c1 += w0 * (float)v0[1] + w1 * (float)v1[1] + w2 * (float)v2[1] + w3 * (float)v3[1];
        c2 += w0 * (float)v0[2] + w1 * (float)v1[2] + w2 * (float)v2[2] + w3 * (float)v3[2];
        c3 += w0 * (float)v0[3] + w1 * (float)v1[3] + w2 * (float)v2[3] + w3 * (float)v3[3];
        c4 += w0 * (float)v0[4] + w1 * (float)v1[4] + w2 * (float)v2[4] + w3 * (float)v3[4];
        c5 += w0 * (float)v0[5] + w1 * (float)v1[5] + w2 * (float)v2[5] + w3 * (float)v3[5];
        c6 += w0 * (float)v0[6] + w1 * (float)v1[6] + w2 * (float)v2[6] + w3 * (float)v3[6];
        c7 += w0 * (float)v0[7] + w1 * (float)v1[7] + w2 * (float)v2[7] + w3 * (float)v3[7];
    }
    for (; k < s1; k += 2) {
        int i0 = col[k];
        float e0 = a_s[i0 * 4 + head];
        half8 v0 = h8[(size_t)i0 * 8 + fl];
        float w0 = __expf(lrelu(e0 + adh) - Mh);
        t += w0;
        c0 += w0 * (float)v0[0]; c1 += w0 * (float)v0[1];
        c2 += w0 * (float)v0[2]; c3 += w0 * (float)v0[3];
        c4 += w0 * (float)v0[4]; c5 += w0 * (float)v0[5];
        c6 += w0 * (float)v0[6]; c7 += w0 * (float)v0[7];
    }
    // single-level reduction: combine the two edge-parity groups (lane ^ 32)
    t  += __shfl_xor(t, 32);
    c0 += __shfl_xor(c0, 32); c1 += __shfl_xor(c1, 32);
    c2 += __shfl_xor(c2, 32); c3 += __shfl_xor(c3, 32);
    c4 += __shfl_xor(c4, 32); c5 += __shfl_xor(c5, 32);
    c6 += __shfl_xor(c6, 32); c7 += __shfl_xor(c7, 32);
    if (grp == 0) {   // lanes 0..31: head*8+fl indexes all 32 output half8 chunks
        float r = 1.f / t;
        half8 o;
        o[0] = (_Float16)(c0 * r); o[1] = (_Float16)(c1 * r);
        o[2] = (_Float16)(c2 * r); o[3] = (_Float16)(c3 * r);
        o[4] = (_Float16)(c4 * r); o[5] = (_Float16)(c5 * r);
        o[6] = (_Float16)(c6 * r); o[7] = (_Float16)(c7 * r);
        ((half8*)(aggH + (size_t)wid * 256))[head * 8 + fl] = o;
    }
}

// ---------------- deferred projection, register-resident W column, fused pooling ----------------

__global__ __launch_bounds__(256) void k_post2(const _Float16* __restrict__ aggH,
                                               const _Float16* __restrict__ W16T,
                                               const float* __restrict__ gat_b,
                                               const int* __restrict__ batch,
                                               float* __restrict__ pool,
                                               float* __restrict__ cnt_g) {
    int tid = threadIdx.x;
    int lane = tid & 63;
    int wv = __builtin_amdgcn_readfirstlane(tid >> 6);
    int h = blockIdx.y;
    int c = h * 64 + lane;                    // global output column
    const float4* wp = (const float4*)(W16T + (size_t)c * 64);
    float4 Wb[8];
#pragma unroll
    for (int i = 0; i < 8; ++i) Wb[i] = wp[i];
    float gb = gat_b[c];

    int rbeg = (blockIdx.x * 4 + wv) * 32;
    int rend = rbeg + 32; if (rend > NN) rend = NN;

    float psum = 0.f;
    int curb = -1, rcnt = 0;
#pragma unroll 2
    for (int row = rbeg; row < rend; ++row) {
        int b = batch[row];
        if (b != curb) {
            if (curb >= 0) {
                atomicAdd(&pool[(size_t)curb * 256 + c], psum);
                if (h == 0 && lane == 0) atomicAdd(&cnt_g[curb], (float)rcnt);
            }
            psum = 0.f; rcnt = 0; curb = b;
        }
        const float4* ap = (const float4*)(aggH + (size_t)row * 256 + h * 64);
        float4 Ab[8];
#pragma unroll
        for (int i = 0; i < 8; ++i) Ab[i] = ap[i];
        float ac0 = 0.f, ac1 = 0.f, ac2 = 0.f, ac3 = 0.f;
#pragma unroll
        for (int i = 0; i < 8; ++i) {
            ac0 = __builtin_amdgcn_fdot2(bch2(Ab[i].x), bch2(Wb[i].x), ac0, false);
            ac1 = __builtin_amdgcn_fdot2(bch2(Ab[i].y), bch2(Wb[i].y), ac1, false);
            ac2 = __builtin_amdgcn_fdot2(bch2(Ab[i].z), bch2(Wb[i].z), ac2, false);
            ac3 = __builtin_amdgcn_fdot2(bch2(Ab[i].w), bch2(Wb[i].w), ac3, false);
        }
        float acc = (ac0 + ac1) + (ac2 + ac3);
        psum += fmaxf(acc + gb, 0.f);
        ++rcnt;
    }
    if (curb >= 0) {
        atomicAdd(&pool[(size_t)curb * 256 + c], psum);
        if (h == 0 && lane == 0) atomicAdd(&cnt_g[curb], (float)rcnt);
    }
}

// ---------------- output projection ----------------

__global__ void k_out(const float* __restrict__ pool, const float* __restrict__ cnt_g,
                      const float* __restrict__ W, const float* __restrict__ b,
                      float* __restrict__ out) {
    int idx = blockIdx.x * blockDim.x + threadIdx.x;
    if (idx >= NGRAPH * NOUT) return;
    int gg = idx >> 5, o = idx & 31;
    float c = cnt_g[gg];
    c = c > 1.f ? c : 1.f;
    float rinv = 1.f / c;
    const float* p = pool + (size_t)gg * 256;
    float acc = 0.f;
#pragma unroll 8
    for (int f = 0; f < 256; ++f) acc += p[f] * W[f * 32 + o];
    out[idx] = acc * rinv + b[o];
}

// ---------------- launch ----------------

extern "C" void kernel_launch(void* const* d_in, const int* in_sizes, int n_in,
                              void* d_out, int out_size, void* d_ws, size_t ws_size,
                              hipStream_t stream) {
    const float* x       = (const float*)d_in[0];
    const int*   eidx    = (const int*)d_in[1];
    const int*   batch   = (const int*)d_in[2];
    const float* gcn_W   = (const float*)d_in[3];
    const float* gcn_b   = (const float*)d_in[4];
    const float* gat_W   = (const float*)d_in[5];
    const float* att_src = (const float*)d_in[6];
    const float* att_dst = (const float*)d_in[7];
    const float* gat_b   = (const float*)d_in[8];
    const float* out_W   = (const float*)d_in[9];
    const float* out_b   = (const float*)d_in[10];
    float* out = (float*)d_out;

    const int* src = eidx;        // edge_index[0]
    const int* dst = eidx + NE;   // edge_index[1]

    size_t off = 0;
    auto carve = [&](size_t bytes) -> char* {
        char* p = (char*)d_ws + off;
        off += (bytes + 255) & ~(size_t)255;
        return p;
    };
    int*      cnt     = (int*)carve(NN * sizeof(int));
    int*      pos     = (int*)carve((size_t)NE * sizeof(int));
    int*      row_ptr = (int*)carve((NN + 1) * sizeof(int));
    int*      bsum    = (int*)carve(256 * sizeof(int));
    int*      colb    = (int*)carve((size_t)NEP * sizeof(int));
    float*    dinv    = (float*)carve(NN * sizeof(float));
    _Float16* hx16    = (_Float16*)carve((size_t)NN * 64 * sizeof(_Float16));
    _Float16* h16     = (_Float16*)carve((size_t)NN * 64 * sizeof(_Float16));
    _Float16* aggH16  = (_Float16*)carve((size_t)NN * 256 * sizeof(_Float16));
    float*    a_s     = (float*)carve((size_t)NN * 4 * sizeof(float));
    float*    a_d     = (float*)carve((size_t)NN * 4 * sizeof(float));
    float*    UV      = (float*)carve(64 * 8 * sizeof(float));
    _Float16* W16T    = (_Float16*)carve(64 * 256 * sizeof(_Float16));
    unsigned* gmaxU   = (unsigned*)carve(4 * sizeof(unsigned));
    float*    pool    = (float*)carve((size_t)NGRAPH * 256 * sizeof(float));
    float*    cnt_g   = (float*)carve(NGRAPH * sizeof(float));

    hipMemsetAsync(cnt, 0, NN * sizeof(int), stream);

    // CSR build (+ weight-side precompute folded into k_scan1)
    k_count<<<(NE + 255) / 256, 256, 0, stream>>>(dst, cnt, pos);
    k_scan1<<<NBLK, 256, 0, stream>>>(cnt, bsum, pool, cnt_g, gmaxU,
                                      gat_W, att_src, att_dst, UV, W16T);
    k_scan3<<<NBLK, 256, 0, stream>>>(cnt, bsum, row_ptr, dinv, colb);
    k_fill<<<(NE + 255) / 256, 256, 0, stream>>>(src, dst, row_ptr, pos, colb);

    // GCN (hx rows pre-scaled by dinv -> agg is pure gather+add; 8-slot dwordx4 gathers)
    k_gemm64<<<(NN + 63) / 64, 256, 0, stream>>>(x, gcn_W, dinv, hx16, NN);
    k_gcn_agg<<<(NN * 64 + 255) / 256, 256, 0, stream>>>(hx16, row_ptr, colb, dinv, gcn_b,
                                                         UV, h16, a_s, a_d);

    // safe softmax bound, then GAT aggregation (head-owned lanes, 1 expf/edge/group)
    k_gmax<<<128, 256, 0, stream>>>(a_s, gmaxU);
    k_gat_h<<<NN / 4, 256, 0, stream>>>(h16, a_s, a_d, row_ptr, colb, gmaxU, aggH16);

    // deferred projection + bias + relu + fused register pooling
    k_post2<<<dim3(391, 4), 256, 0, stream>>>(aggH16, W16T, gat_b, batch, pool, cnt_g);

    // output projection
    k_out<<<(NGRAPH * NOUT + 255) / 256, 256, 0, stream>>>(pool, cnt_g, out_W, out_b, out);
}